// Round 1
// baseline (1979.104 us; speedup 1.0000x reference)
//
#include <hip/hip_runtime.h>
#include <math.h>

#define N_NODES 50000
#define N_EDGES 800000
#define EA (N_EDGES + N_NODES)   /* edges + self loops = 850000 */
#define HEADS 4
#define HID 64
#define NG 64
#define NEG_SLOPE 0.2f

__device__ inline void atomicMaxF(float* addr, float val) {
    // ordered-bits trick: positives compare as int, negatives as unsigned (min)
    if (val >= 0.f) atomicMax((int*)addr, __float_as_int(val));
    else            atomicMin((unsigned int*)addr, __float_as_uint(val));
}
__device__ inline float lrelu(float x) { return x > 0.f ? x : NEG_SLOPE * x; }

__device__ inline void edge_sd(const int* __restrict__ ei, int e, int& s, int& d) {
    if (e < N_EDGES) { s = ei[e]; d = ei[N_EDGES + e]; }
    else { s = e - N_EDGES; d = s; }
}

// ---------------- conv1: xp1 = x @ W1 ; per-(node,head) scores ----------------
__global__ __launch_bounds__(256) void k_gemm1(const float* __restrict__ x,
        const float* __restrict__ W1, const float* __restrict__ a1s_g,
        const float* __restrict__ a1d_g, float* __restrict__ xp1,
        float* __restrict__ e1s, float* __restrict__ e1d)
{
    __shared__ float sW[64 * 256];    // 64 KB
    __shared__ float sx[16][64];
    const int t = threadIdx.x;
    for (int i = t; i < 64 * 256; i += 256) sW[i] = W1[i];
    const float as = a1s_g[t];   // t = h*64 + c
    const float ad = a1d_g[t];
    const int row0 = blockIdx.x * 16;
    for (int i = t; i < 16 * 64; i += 256) {
        int r = i >> 6, c = i & 63;
        sx[r][c] = x[(size_t)(row0 + r) * 64 + c];
    }
    __syncthreads();
    const int lane = t & 63;
    const int h = t >> 6;
    for (int r = 0; r < 16; ++r) {
        float acc = 0.f;
        #pragma unroll
        for (int k = 0; k < 64; ++k) acc = fmaf(sx[r][k], sW[k * 256 + t], acc);
        xp1[(size_t)(row0 + r) * 256 + t] = acc;
        float ps = acc * as, pd = acc * ad;
        #pragma unroll
        for (int off = 32; off > 0; off >>= 1) {
            ps += __shfl_down(ps, off, 64);
            pd += __shfl_down(pd, off, 64);
        }
        if (lane == 0) {
            e1s[(row0 + r) * HEADS + h] = ps;
            e1d[(row0 + r) * HEADS + h] = pd;
        }
    }
}

__global__ void k_init1(float* __restrict__ m1, float* __restrict__ d1,
                        float* __restrict__ out1)
{
    int i = blockIdx.x * blockDim.x + threadIdx.x;
    int stride = gridDim.x * blockDim.x;
    for (int j = i; j < N_NODES * HEADS; j += stride) { m1[j] = -INFINITY; d1[j] = 0.f; }
    for (size_t j = i; j < (size_t)N_NODES * 256; j += stride) out1[j] = 0.f;
}

__global__ void k_max1(const int* __restrict__ ei, const float* __restrict__ e1s,
                       const float* __restrict__ e1d, float* __restrict__ m1)
{
    int e = blockIdx.x * blockDim.x + threadIdx.x;
    if (e >= EA) return;
    int s, d; edge_sd(ei, e, s, d);
    float4 vs = *(const float4*)(e1s + (size_t)s * 4);
    float4 vd = *(const float4*)(e1d + (size_t)d * 4);
    atomicMaxF(&m1[d * 4 + 0], lrelu(vs.x + vd.x));
    atomicMaxF(&m1[d * 4 + 1], lrelu(vs.y + vd.y));
    atomicMaxF(&m1[d * 4 + 2], lrelu(vs.z + vd.z));
    atomicMaxF(&m1[d * 4 + 3], lrelu(vs.w + vd.w));
}

__global__ void k_sum1(const int* __restrict__ ei, const float* __restrict__ e1s,
                       const float* __restrict__ e1d, const float* __restrict__ m1,
                       float* __restrict__ d1)
{
    int e = blockIdx.x * blockDim.x + threadIdx.x;
    if (e >= EA) return;
    int s, d; edge_sd(ei, e, s, d);
    float4 vs = *(const float4*)(e1s + (size_t)s * 4);
    float4 vd = *(const float4*)(e1d + (size_t)d * 4);
    float4 vm = *(const float4*)(m1 + (size_t)d * 4);
    atomicAdd(&d1[d * 4 + 0], expf(lrelu(vs.x + vd.x) - vm.x));
    atomicAdd(&d1[d * 4 + 1], expf(lrelu(vs.y + vd.y) - vm.y));
    atomicAdd(&d1[d * 4 + 2], expf(lrelu(vs.z + vd.z) - vm.z));
    atomicAdd(&d1[d * 4 + 3], expf(lrelu(vs.w + vd.w) - vm.w));
}

// wave per edge: 4 heads x 64 channels, atomic scatter into out1[dst]
__global__ __launch_bounds__(256) void k_aggr1(const int* __restrict__ ei,
        const float* __restrict__ e1s, const float* __restrict__ e1d,
        const float* __restrict__ m1, const float* __restrict__ d1,
        const float* __restrict__ xp1, float* __restrict__ out1)
{
    int w = threadIdx.x >> 6, lane = threadIdx.x & 63;
    int e = blockIdx.x * 4 + w;
    if (e >= EA) return;
    int s, d; edge_sd(ei, e, s, d);
    float4 vs = *(const float4*)(e1s + (size_t)s * 4);
    float4 vd = *(const float4*)(e1d + (size_t)d * 4);
    float4 vm = *(const float4*)(m1 + (size_t)d * 4);
    float4 vq = *(const float4*)(d1 + (size_t)d * 4);
    float a0 = expf(lrelu(vs.x + vd.x) - vm.x) / vq.x;
    float a1 = expf(lrelu(vs.y + vd.y) - vm.y) / vq.y;
    float a2 = expf(lrelu(vs.z + vd.z) - vm.z) / vq.z;
    float a3 = expf(lrelu(vs.w + vd.w) - vm.w) / vq.w;
    const float* xs = xp1 + (size_t)s * 256;
    float* od = out1 + (size_t)d * 256;
    atomicAdd(od + lane,        a0 * xs[lane]);
    atomicAdd(od + 64  + lane,  a1 * xs[64 + lane]);
    atomicAdd(od + 128 + lane,  a2 * xs[128 + lane]);
    atomicAdd(od + 192 + lane,  a3 * xs[192 + lane]);
}

// -------- conv2 gemm: xp2 = elu(out1 + b1) @ W2, fused scores --------
__global__ __launch_bounds__(256) void k_gemm2(const float* __restrict__ out1,
        const float* __restrict__ b1, const float* __restrict__ W2,
        const float* __restrict__ a2s_g, const float* __restrict__ a2d_g,
        float* __restrict__ xp2, float* __restrict__ e2s, float* __restrict__ e2d)
{
    __shared__ float sW[256 * HID];   // 64 KB
    __shared__ float sb[256];
    __shared__ float sh[4][256];
    const int t = threadIdx.x;
    for (int i = t; i < 256 * HID; i += 256) sW[i] = W2[i];
    sb[t] = b1[t];
    __syncthreads();
    const int w = t >> 6, lane = t & 63;
    const float as = a2s_g[lane], ad = a2d_g[lane];
    const int row0 = blockIdx.x * 32;
    for (int i = 0; i < 8; ++i) {
        int r = row0 + i * 4 + w;
        if (r >= N_NODES) continue;
        #pragma unroll
        for (int j = 0; j < 4; ++j) {
            int k = lane + j * 64;
            float v = out1[(size_t)r * 256 + k] + sb[k];
            sh[w][k] = v > 0.f ? v : expm1f(v);
        }
        float acc = 0.f;
        for (int k = 0; k < 256; ++k) acc = fmaf(sh[w][k], sW[k * HID + lane], acc);
        xp2[(size_t)r * HID + lane] = acc;
        float ps = acc * as, pd = acc * ad;
        #pragma unroll
        for (int off = 32; off > 0; off >>= 1) {
            ps += __shfl_down(ps, off, 64);
            pd += __shfl_down(pd, off, 64);
        }
        if (lane == 0) { e2s[r] = ps; e2d[r] = pd; }
    }
}

__global__ void k_init2(float* __restrict__ m2, float* __restrict__ d2,
                        float* __restrict__ out2, float* __restrict__ pooled,
                        float* __restrict__ cnt)
{
    int i = blockIdx.x * blockDim.x + threadIdx.x;
    int stride = gridDim.x * blockDim.x;
    for (int j = i; j < N_NODES; j += stride) { m2[j] = -INFINITY; d2[j] = 0.f; }
    for (size_t j = i; j < (size_t)N_NODES * HID; j += stride) out2[j] = 0.f;
    for (int j = i; j < NG * HID; j += stride) pooled[j] = 0.f;
    for (int j = i; j < NG; j += stride) cnt[j] = 0.f;
}

__global__ void k_max2(const int* __restrict__ ei, const float* __restrict__ e2s,
                       const float* __restrict__ e2d, float* __restrict__ m2)
{
    int e = blockIdx.x * blockDim.x + threadIdx.x;
    if (e >= EA) return;
    int s, d; edge_sd(ei, e, s, d);
    atomicMaxF(&m2[d], lrelu(e2s[s] + e2d[d]));
}

__global__ void k_sum2(const int* __restrict__ ei, const float* __restrict__ e2s,
                       const float* __restrict__ e2d, const float* __restrict__ m2,
                       float* __restrict__ d2)
{
    int e = blockIdx.x * blockDim.x + threadIdx.x;
    if (e >= EA) return;
    int s, d; edge_sd(ei, e, s, d);
    atomicAdd(&d2[d], expf(lrelu(e2s[s] + e2d[d]) - m2[d]));
}

__global__ __launch_bounds__(256) void k_aggr2(const int* __restrict__ ei,
        const float* __restrict__ e2s, const float* __restrict__ e2d,
        const float* __restrict__ m2, const float* __restrict__ d2,
        const float* __restrict__ xp2, float* __restrict__ out2)
{
    int w = threadIdx.x >> 6, lane = threadIdx.x & 63;
    int e = blockIdx.x * 4 + w;
    if (e >= EA) return;
    int s, d; edge_sd(ei, e, s, d);
    float al = expf(lrelu(e2s[s] + e2d[d]) - m2[d]) / d2[d];
    atomicAdd(out2 + (size_t)d * HID + lane, al * xp2[(size_t)s * HID + lane]);
}

__global__ void k_pool(const int* __restrict__ batch, const float* __restrict__ out2,
                       const float* __restrict__ b2, float* __restrict__ pooled,
                       float* __restrict__ cnt)
{
    int i = blockIdx.x * blockDim.x + threadIdx.x;
    int stride = gridDim.x * blockDim.x;
    for (size_t j = i; j < (size_t)N_NODES * HID; j += stride) {
        int n = (int)(j >> 6), c = (int)(j & 63);
        int g = batch[n];
        atomicAdd(&pooled[g * HID + c], out2[j] + b2[c]);
        if (c == 0) atomicAdd(&cnt[g], 1.f);
    }
}

__global__ void k_mlp(const float* __restrict__ pooled, const float* __restrict__ cnt,
                      const float* __restrict__ Wh1, const float* __restrict__ bh1,
                      const float* __restrict__ Wh2, const float* __restrict__ bh2,
                      float* __restrict__ out)
{
    int g = threadIdx.x;   // 64 threads
    float inv = 1.f / fmaxf(cnt[g], 1.f);
    float p[64];
    #pragma unroll
    for (int c = 0; c < 64; ++c) p[c] = pooled[g * 64 + c] * inv;
    float acc2 = bh2[0];
    for (int j = 0; j < 16; ++j) {
        float z = bh1[j];
        #pragma unroll
        for (int c = 0; c < 64; ++c) z = fmaf(p[c], Wh1[c * 16 + j], z);
        z = fmaxf(z, 0.f);
        acc2 = fmaf(z, Wh2[j], acc2);
    }
    out[g] = 1.f / (1.f + expf(-acc2));
}

extern "C" void kernel_launch(void* const* d_in, const int* in_sizes, int n_in,
                              void* d_out, int out_size, void* d_ws, size_t ws_size,
                              hipStream_t stream)
{
    const float* x      = (const float*)d_in[0];
    const int*   ei     = (const int*)d_in[1];
    const int*   batch  = (const int*)d_in[2];
    const float* W1     = (const float*)d_in[3];
    const float* a1s    = (const float*)d_in[4];
    const float* a1d    = (const float*)d_in[5];
    const float* b1     = (const float*)d_in[6];
    const float* W2     = (const float*)d_in[7];
    const float* a2s    = (const float*)d_in[8];
    const float* a2d    = (const float*)d_in[9];
    const float* b2     = (const float*)d_in[10];
    const float* Wh1    = (const float*)d_in[11];
    const float* bh1    = (const float*)d_in[12];
    const float* Wh2    = (const float*)d_in[13];
    const float* bh2    = (const float*)d_in[14];
    float* out = (float*)d_out;

    float* ws   = (float*)d_ws;
    float* xp1  = ws;                               // N*256
    float* out1 = xp1 + (size_t)N_NODES * 256;      // N*256
    float* e1s  = out1 + (size_t)N_NODES * 256;     // N*4
    float* e1d  = e1s + (size_t)N_NODES * 4;
    float* m1   = e1d + (size_t)N_NODES * 4;
    float* d1   = m1  + (size_t)N_NODES * 4;
    float* pooled = d1 + (size_t)N_NODES * 4;       // 64*64
    float* cnt    = pooled + NG * HID;              // 64
    // conv2 buffers alias the (dead-after-aggr1) xp1 region
    float* xp2  = xp1;                              // N*64
    float* out2 = xp1 + (size_t)N_NODES * 64;       // N*64
    float* e2s  = xp1 + (size_t)N_NODES * 128;      // N
    float* e2d  = e2s + N_NODES;
    float* m2   = e2d + N_NODES;
    float* d2   = m2  + N_NODES;

    const int BE = (EA + 255) / 256;

    hipLaunchKernelGGL(k_gemm1, dim3(N_NODES / 16), dim3(256), 0, stream,
                       x, W1, a1s, a1d, xp1, e1s, e1d);
    hipLaunchKernelGGL(k_init1, dim3(2048), dim3(256), 0, stream, m1, d1, out1);
    hipLaunchKernelGGL(k_max1, dim3(BE), dim3(256), 0, stream, ei, e1s, e1d, m1);
    hipLaunchKernelGGL(k_sum1, dim3(BE), dim3(256), 0, stream, ei, e1s, e1d, m1, d1);
    hipLaunchKernelGGL(k_aggr1, dim3((EA + 3) / 4), dim3(256), 0, stream,
                       ei, e1s, e1d, m1, d1, xp1, out1);
    hipLaunchKernelGGL(k_gemm2, dim3((N_NODES + 31) / 32), dim3(256), 0, stream,
                       out1, b1, W2, a2s, a2d, xp2, e2s, e2d);
    hipLaunchKernelGGL(k_init2, dim3(2048), dim3(256), 0, stream, m2, d2, out2, pooled, cnt);
    hipLaunchKernelGGL(k_max2, dim3(BE), dim3(256), 0, stream, ei, e2s, e2d, m2);
    hipLaunchKernelGGL(k_sum2, dim3(BE), dim3(256), 0, stream, ei, e2s, e2d, m2, d2);
    hipLaunchKernelGGL(k_aggr2, dim3((EA + 3) / 4), dim3(256), 0, stream,
                       ei, e2s, e2d, m2, d2, xp2, out2);
    hipLaunchKernelGGL(k_pool, dim3(1024), dim3(256), 0, stream,
                       batch, out2, b2, pooled, cnt);
    hipLaunchKernelGGL(k_mlp, dim3(1), dim3(64), 0, stream,
                       pooled, cnt, Wh1, bh1, Wh2, bh2, out);
}

// Round 2
// 739.546 us; speedup vs baseline: 2.6761x; 2.6761x over previous
//
#include <hip/hip_runtime.h>
#include <math.h>

#define N_NODES 50000
#define N_EDGES 800000
#define EA (N_EDGES + N_NODES)   /* edges + self loops = 850000 */
#define HEADS 4
#define HID 64
#define NG 64
#define NEG_SLOPE 0.2f
#define SCAN_CHUNK 1024
#define NBLK ((N_NODES + SCAN_CHUNK - 1) / SCAN_CHUNK)   /* 49 */

__device__ inline float lrelu(float x) { return x > 0.f ? x : NEG_SLOPE * x; }

__device__ inline void edge_sd(const int* __restrict__ ei, int e, int& s, int& d) {
    if (e < N_EDGES) { s = ei[e]; d = ei[N_EDGES + e]; }
    else { s = e - N_EDGES; d = s; }
}

// ---------------- CSR build ----------------
__global__ void k_zero(int* __restrict__ deg, float* __restrict__ pooled,
                       float* __restrict__ cnt)
{
    int i = blockIdx.x * 256 + threadIdx.x;
    int st = gridDim.x * 256;
    for (int j = i; j < N_NODES; j += st) deg[j] = 0;
    if (i < NG * HID) pooled[i] = 0.f;
    if (i < NG) cnt[i] = 0.f;
}

__global__ void k_deg(const int* __restrict__ ei, int* __restrict__ deg)
{
    int e = blockIdx.x * 256 + threadIdx.x;
    if (e >= EA) return;
    int s, d; edge_sd(ei, e, s, d);
    atomicAdd(&deg[d], 1);
}

__global__ __launch_bounds__(1024) void k_scan1(const int* __restrict__ deg,
        int* __restrict__ incl, int* __restrict__ blksum)
{
    __shared__ int sd[SCAN_CHUNK];
    int t = threadIdx.x;
    int i = blockIdx.x * SCAN_CHUNK + t;
    sd[t] = (i < N_NODES) ? deg[i] : 0;
    for (int off = 1; off < SCAN_CHUNK; off <<= 1) {
        __syncthreads();
        int u = (t >= off) ? sd[t - off] : 0;
        __syncthreads();
        sd[t] += u;
    }
    if (i < N_NODES) incl[i] = sd[t];
    if (t == SCAN_CHUNK - 1) blksum[blockIdx.x] = sd[t];
}

__global__ void k_scan2(const int* __restrict__ blksum, int* __restrict__ blkoff)
{
    if (threadIdx.x == 0) {
        int acc = 0;
        for (int b = 0; b < NBLK; ++b) { blkoff[b] = acc; acc += blksum[b]; }
    }
}

__global__ void k_scan3(const int* __restrict__ incl, const int* __restrict__ blkoff,
                        const int* __restrict__ deg, const int* __restrict__ batch,
                        int* __restrict__ rowptr, int* __restrict__ cursor,
                        float* __restrict__ cnt)
{
    int i = blockIdx.x * 256 + threadIdx.x;
    bool act = i < N_NODES;
    if (act) {
        int v = incl[i] + blkoff[i >> 10];
        rowptr[i + 1] = v;
        cursor[i] = v - deg[i];
        if (i == 0) rowptr[0] = 0;
    }
    // graph node counts, wave-aggregated (batch is sorted)
    int g = act ? batch[i] : -1;
    int lane = threadIdx.x & 63;
    int g0 = __shfl(g, 0, 64);
    if (__all(g == g0)) {
        if (lane == 0 && g0 >= 0) atomicAdd(&cnt[g0], 64.f);
    } else if (act) {
        atomicAdd(&cnt[g], 1.f);
    }
}

__global__ void k_fill(const int* __restrict__ ei, int* __restrict__ cursor,
                       int* __restrict__ csr_src)
{
    int e = blockIdx.x * 256 + threadIdx.x;
    if (e >= EA) return;
    int s, d; edge_sd(ei, e, s, d);
    int pos = atomicAdd(&cursor[d], 1);
    csr_src[pos] = s;
}

// ---------------- conv1 ----------------
__global__ __launch_bounds__(256) void k_gemm1(const float* __restrict__ x,
        const float* __restrict__ W1, const float* __restrict__ a1s_g,
        const float* __restrict__ a1d_g, float* __restrict__ xp1,
        float* __restrict__ e1s, float* __restrict__ e1d)
{
    __shared__ float sW[64 * 256];    // 64 KB
    __shared__ float sx[16][64];
    const int t = threadIdx.x;
    for (int i = t; i < 64 * 256; i += 256) sW[i] = W1[i];
    const float as = a1s_g[t];   // t = h*64 + c
    const float ad = a1d_g[t];
    const int row0 = blockIdx.x * 16;
    for (int i = t; i < 16 * 64; i += 256) {
        int r = i >> 6, c = i & 63;
        sx[r][c] = x[(size_t)(row0 + r) * 64 + c];
    }
    __syncthreads();
    const int lane = t & 63;
    const int h = t >> 6;
    for (int r = 0; r < 16; ++r) {
        float acc = 0.f;
        #pragma unroll
        for (int k = 0; k < 64; ++k) acc = fmaf(sx[r][k], sW[k * 256 + t], acc);
        xp1[(size_t)(row0 + r) * 256 + t] = acc;
        float ps = acc * as, pd = acc * ad;
        #pragma unroll
        for (int off = 32; off > 0; off >>= 1) {
            ps += __shfl_down(ps, off, 64);
            pd += __shfl_down(pd, off, 64);
        }
        if (lane == 0) {
            e1s[(row0 + r) * HEADS + h] = ps;
            e1d[(row0 + r) * HEADS + h] = pd;
        }
    }
}

__global__ void k_msum1(const int* __restrict__ rowptr, const int* __restrict__ csr_src,
                        const float* __restrict__ e1s, const float* __restrict__ e1d,
                        float* __restrict__ rm, float* __restrict__ rinv)
{
    int d = blockIdx.x * 256 + threadIdx.x;
    if (d >= N_NODES) return;
    int beg = rowptr[d], end = rowptr[d + 1];
    float4 ed = ((const float4*)e1d)[d];
    float4 m = make_float4(-INFINITY, -INFINITY, -INFINITY, -INFINITY);
    for (int j = beg; j < end; ++j) {
        int s = csr_src[j];
        float4 q = ((const float4*)e1s)[s];
        m.x = fmaxf(m.x, lrelu(q.x + ed.x));
        m.y = fmaxf(m.y, lrelu(q.y + ed.y));
        m.z = fmaxf(m.z, lrelu(q.z + ed.z));
        m.w = fmaxf(m.w, lrelu(q.w + ed.w));
    }
    float4 sum = make_float4(0.f, 0.f, 0.f, 0.f);
    for (int j = beg; j < end; ++j) {
        int s = csr_src[j];
        float4 q = ((const float4*)e1s)[s];
        sum.x += expf(lrelu(q.x + ed.x) - m.x);
        sum.y += expf(lrelu(q.y + ed.y) - m.y);
        sum.z += expf(lrelu(q.z + ed.z) - m.z);
        sum.w += expf(lrelu(q.w + ed.w) - m.w);
    }
    ((float4*)rm)[d] = m;
    float4 iv = make_float4(1.f / sum.x, 1.f / sum.y, 1.f / sum.z, 1.f / sum.w);
    ((float4*)rinv)[d] = iv;
}

// wave per dst node: gather + register accumulate + single coalesced write
__global__ __launch_bounds__(256) void k_aggr1(const int* __restrict__ rowptr,
        const int* __restrict__ csr_src, const float* __restrict__ e1s,
        const float* __restrict__ e1d, const float* __restrict__ rm,
        const float* __restrict__ rinv, const float* __restrict__ xp1,
        float* __restrict__ out1)
{
    int w = threadIdx.x >> 6, lane = threadIdx.x & 63;
    int d = blockIdx.x * 4 + w;
    if (d >= N_NODES) return;
    int beg = rowptr[d], end = rowptr[d + 1];
    float4 ed = ((const float4*)e1d)[d];
    float4 m = ((const float4*)rm)[d];
    float4 iv = ((const float4*)rinv)[d];
    float a0 = 0.f, a1 = 0.f, a2 = 0.f, a3 = 0.f;
    for (int j = beg; j < end; ++j) {
        int s = csr_src[j];
        float4 q = ((const float4*)e1s)[s];
        float p0 = expf(lrelu(q.x + ed.x) - m.x);
        float p1 = expf(lrelu(q.y + ed.y) - m.y);
        float p2 = expf(lrelu(q.z + ed.z) - m.z);
        float p3 = expf(lrelu(q.w + ed.w) - m.w);
        const float* xs = xp1 + (size_t)s * 256;
        a0 = fmaf(p0, xs[lane],        a0);
        a1 = fmaf(p1, xs[64  + lane],  a1);
        a2 = fmaf(p2, xs[128 + lane],  a2);
        a3 = fmaf(p3, xs[192 + lane],  a3);
    }
    float* od = out1 + (size_t)d * 256;
    od[lane]        = a0 * iv.x;
    od[64  + lane]  = a1 * iv.y;
    od[128 + lane]  = a2 * iv.z;
    od[192 + lane]  = a3 * iv.w;
}

// -------- conv2 gemm: xp2 = elu(out1 + b1) @ W2, fused scores --------
__global__ __launch_bounds__(256) void k_gemm2(const float* __restrict__ out1,
        const float* __restrict__ b1, const float* __restrict__ W2,
        const float* __restrict__ a2s_g, const float* __restrict__ a2d_g,
        float* __restrict__ xp2, float* __restrict__ e2s, float* __restrict__ e2d)
{
    __shared__ float sW[256 * HID];   // 64 KB
    __shared__ float sb[256];
    __shared__ float sh[4][256];
    const int t = threadIdx.x;
    for (int i = t; i < 256 * HID; i += 256) sW[i] = W2[i];
    sb[t] = b1[t];
    __syncthreads();
    const int w = t >> 6, lane = t & 63;
    const float as = a2s_g[lane], ad = a2d_g[lane];
    const int row0 = blockIdx.x * 32;
    for (int i = 0; i < 8; ++i) {
        int r = row0 + i * 4 + w;
        if (r >= N_NODES) continue;
        #pragma unroll
        for (int j = 0; j < 4; ++j) {
            int k = lane + j * 64;
            float v = out1[(size_t)r * 256 + k] + sb[k];
            sh[w][k] = v > 0.f ? v : expm1f(v);
        }
        float acc = 0.f;
        for (int k = 0; k < 256; ++k) acc = fmaf(sh[w][k], sW[k * HID + lane], acc);
        xp2[(size_t)r * HID + lane] = acc;
        float ps = acc * as, pd = acc * ad;
        #pragma unroll
        for (int off = 32; off > 0; off >>= 1) {
            ps += __shfl_down(ps, off, 64);
            pd += __shfl_down(pd, off, 64);
        }
        if (lane == 0) { e2s[r] = ps; e2d[r] = pd; }
    }
}

__global__ void k_msum2(const int* __restrict__ rowptr, const int* __restrict__ csr_src,
                        const float* __restrict__ e2s, const float* __restrict__ e2d,
                        float* __restrict__ rm2, float* __restrict__ rinv2)
{
    int d = blockIdx.x * 256 + threadIdx.x;
    if (d >= N_NODES) return;
    int beg = rowptr[d], end = rowptr[d + 1];
    float ed = e2d[d];
    float m = -INFINITY;
    for (int j = beg; j < end; ++j) m = fmaxf(m, lrelu(e2s[csr_src[j]] + ed));
    float sum = 0.f;
    for (int j = beg; j < end; ++j) sum += expf(lrelu(e2s[csr_src[j]] + ed) - m);
    rm2[d] = m;
    rinv2[d] = 1.f / sum;
}

// wave per dst, fused global mean-pool accumulation (out2 never materialized)
__global__ __launch_bounds__(256) void k_aggr2(const int* __restrict__ rowptr,
        const int* __restrict__ csr_src, const float* __restrict__ e2s,
        const float* __restrict__ e2d, const float* __restrict__ rm2,
        const float* __restrict__ rinv2, const float* __restrict__ xp2,
        const int* __restrict__ batch, const float* __restrict__ b2,
        float* __restrict__ pooled)
{
    int w = threadIdx.x >> 6, lane = threadIdx.x & 63;
    int d = blockIdx.x * 4 + w;
    if (d >= N_NODES) return;
    int beg = rowptr[d], end = rowptr[d + 1];
    float ed = e2d[d], m = rm2[d], iv = rinv2[d];
    float acc = 0.f;
    for (int j = beg; j < end; ++j) {
        int s = csr_src[j];
        float p = expf(lrelu(e2s[s] + ed) - m);
        acc = fmaf(p, xp2[(size_t)s * HID + lane], acc);
    }
    float val = acc * iv + b2[lane];
    int g = batch[d];
    atomicAdd(&pooled[(size_t)g * HID + lane], val);
}

__global__ void k_mlp(const float* __restrict__ pooled, const float* __restrict__ cnt,
                      const float* __restrict__ Wh1, const float* __restrict__ bh1,
                      const float* __restrict__ Wh2, const float* __restrict__ bh2,
                      float* __restrict__ out)
{
    int g = threadIdx.x;   // 64 threads
    float inv = 1.f / fmaxf(cnt[g], 1.f);
    float p[64];
    #pragma unroll
    for (int c = 0; c < 64; ++c) p[c] = pooled[g * 64 + c] * inv;
    float acc2 = bh2[0];
    for (int j = 0; j < 16; ++j) {
        float z = bh1[j];
        #pragma unroll
        for (int c = 0; c < 64; ++c) z = fmaf(p[c], Wh1[c * 16 + j], z);
        z = fmaxf(z, 0.f);
        acc2 = fmaf(z, Wh2[j], acc2);
    }
    out[g] = 1.f / (1.f + expf(-acc2));
}

extern "C" void kernel_launch(void* const* d_in, const int* in_sizes, int n_in,
                              void* d_out, int out_size, void* d_ws, size_t ws_size,
                              hipStream_t stream)
{
    const float* x      = (const float*)d_in[0];
    const int*   ei     = (const int*)d_in[1];
    const int*   batch  = (const int*)d_in[2];
    const float* W1     = (const float*)d_in[3];
    const float* a1s    = (const float*)d_in[4];
    const float* a1d    = (const float*)d_in[5];
    const float* b1     = (const float*)d_in[6];
    const float* W2     = (const float*)d_in[7];
    const float* a2s    = (const float*)d_in[8];
    const float* a2d    = (const float*)d_in[9];
    const float* b2     = (const float*)d_in[10];
    const float* Wh1    = (const float*)d_in[11];
    const float* bh1    = (const float*)d_in[12];
    const float* Wh2    = (const float*)d_in[13];
    const float* bh2    = (const float*)d_in[14];
    float* out = (float*)d_out;

    float* ws    = (float*)d_ws;
    float* xp1   = ws;                                // N*256
    float* out1  = ws + (size_t)N_NODES * 256;        // N*256
    float* e1s   = ws + (size_t)N_NODES * 512;        // N*4
    float* e1d   = e1s  + (size_t)N_NODES * 4;
    float* rm1   = e1d  + (size_t)N_NODES * 4;
    float* rinv1 = rm1  + (size_t)N_NODES * 4;
    float* pooled= rinv1+ (size_t)N_NODES * 4;        // 64*64
    float* cnt   = pooled + NG * HID;                 // 64
    int* rowptr  = (int*)(cnt + NG);                  // N+1
    int* cursor  = rowptr + N_NODES + 1;              // N
    int* csr_src = cursor + N_NODES;                  // EA
    int* blksum  = csr_src + EA;                      // NBLK
    int* blkoff  = blksum + NBLK;                     // NBLK
    // deg/incl alias the (not-yet-written) out1 region
    int* deg  = (int*)out1;
    int* incl = deg + N_NODES;
    // conv2 buffers alias the (dead-after-aggr1) xp1 region
    float* xp2   = xp1;                               // N*64
    float* e2s   = xp1 + (size_t)N_NODES * 64;        // N
    float* e2d   = e2s + N_NODES;
    float* rm2   = e2d + N_NODES;
    float* rinv2 = rm2 + N_NODES;

    const int BE = (EA + 255) / 256;
    const int BN = (N_NODES + 255) / 256;

    hipLaunchKernelGGL(k_zero,  dim3(64),  dim3(256), 0, stream, deg, pooled, cnt);
    hipLaunchKernelGGL(k_deg,   dim3(BE),  dim3(256), 0, stream, ei, deg);
    hipLaunchKernelGGL(k_scan1, dim3(NBLK),dim3(1024),0, stream, deg, incl, blksum);
    hipLaunchKernelGGL(k_scan2, dim3(1),   dim3(64),  0, stream, blksum, blkoff);
    hipLaunchKernelGGL(k_scan3, dim3(BN),  dim3(256), 0, stream,
                       incl, blkoff, deg, batch, rowptr, cursor, cnt);
    hipLaunchKernelGGL(k_fill,  dim3(BE),  dim3(256), 0, stream, ei, cursor, csr_src);

    hipLaunchKernelGGL(k_gemm1, dim3(N_NODES / 16), dim3(256), 0, stream,
                       x, W1, a1s, a1d, xp1, e1s, e1d);
    hipLaunchKernelGGL(k_msum1, dim3(BN), dim3(256), 0, stream,
                       rowptr, csr_src, e1s, e1d, rm1, rinv1);
    hipLaunchKernelGGL(k_aggr1, dim3((N_NODES + 3) / 4), dim3(256), 0, stream,
                       rowptr, csr_src, e1s, e1d, rm1, rinv1, xp1, out1);

    hipLaunchKernelGGL(k_gemm2, dim3((N_NODES + 31) / 32), dim3(256), 0, stream,
                       out1, b1, W2, a2s, a2d, xp2, e2s, e2d);
    hipLaunchKernelGGL(k_msum2, dim3(BN), dim3(256), 0, stream,
                       rowptr, csr_src, e2s, e2d, rm2, rinv2);
    hipLaunchKernelGGL(k_aggr2, dim3((N_NODES + 3) / 4), dim3(256), 0, stream,
                       rowptr, csr_src, e2s, e2d, rm2, rinv2, xp2, batch, b2, pooled);

    hipLaunchKernelGGL(k_mlp, dim3(1), dim3(64), 0, stream,
                       pooled, cnt, Wh1, bh1, Wh2, bh2, out);
}

// Round 4
// 611.884 us; speedup vs baseline: 3.2344x; 1.2086x over previous
//
#include <hip/hip_runtime.h>
#include <math.h>

#define N_NODES 50000
#define N_EDGES 800000
#define EA (N_EDGES + N_NODES)   /* edges + self loops = 850000 */
#define HEADS 4
#define HID 64
#define NG 64
#define NEG_SLOPE 0.2f
#define SCAN_CHUNK 1024
#define NBLK ((N_NODES + SCAN_CHUNK - 1) / SCAN_CHUNK)   /* 49 */

__device__ inline float lrelu(float x) { return x > 0.f ? x : NEG_SLOPE * x; }

__device__ inline void edge_sd(const int* __restrict__ ei, int e, int& s, int& d) {
    if (e < N_EDGES) { s = ei[e]; d = ei[N_EDGES + e]; }
    else { s = e - N_EDGES; d = s; }
}

// ---------------- CSR build ----------------
__global__ void k_zero(int* __restrict__ deg, float* __restrict__ pooled,
                       float* __restrict__ cnt)
{
    int i = blockIdx.x * 256 + threadIdx.x;
    int st = gridDim.x * 256;
    for (int j = i; j < N_NODES; j += st) deg[j] = 0;
    if (i < NG * HID) pooled[i] = 0.f;
    if (i < NG) cnt[i] = 0.f;
}

__global__ void k_deg(const int* __restrict__ ei, int* __restrict__ deg)
{
    int e = blockIdx.x * 256 + threadIdx.x;
    if (e >= EA) return;
    int s, d; edge_sd(ei, e, s, d);
    atomicAdd(&deg[d], 1);
}

__global__ __launch_bounds__(1024) void k_scan1(const int* __restrict__ deg,
        int* __restrict__ incl, int* __restrict__ blksum)
{
    __shared__ int sd[SCAN_CHUNK];
    int t = threadIdx.x;
    int i = blockIdx.x * SCAN_CHUNK + t;
    sd[t] = (i < N_NODES) ? deg[i] : 0;
    for (int off = 1; off < SCAN_CHUNK; off <<= 1) {
        __syncthreads();
        int u = (t >= off) ? sd[t - off] : 0;
        __syncthreads();
        sd[t] += u;
    }
    if (i < N_NODES) incl[i] = sd[t];
    if (t == SCAN_CHUNK - 1) blksum[blockIdx.x] = sd[t];
}

__global__ void k_scan2(const int* __restrict__ blksum, int* __restrict__ blkoff)
{
    if (threadIdx.x == 0) {
        int acc = 0;
        for (int b = 0; b < NBLK; ++b) { blkoff[b] = acc; acc += blksum[b]; }
    }
}

__global__ void k_scan3(const int* __restrict__ incl, const int* __restrict__ blkoff,
                        const int* __restrict__ deg, const int* __restrict__ batch,
                        int* __restrict__ rowptr, int* __restrict__ cursor,
                        float* __restrict__ cnt)
{
    int i = blockIdx.x * 256 + threadIdx.x;
    bool act = i < N_NODES;
    if (act) {
        int v = incl[i] + blkoff[i >> 10];
        rowptr[i + 1] = v;
        cursor[i] = v - deg[i];
        if (i == 0) rowptr[0] = 0;
    }
    int g = act ? batch[i] : -1;
    int lane = threadIdx.x & 63;
    int g0 = __shfl(g, 0, 64);
    if (__all(g == g0)) {
        if (lane == 0 && g0 >= 0) atomicAdd(&cnt[g0], 64.f);
    } else if (act) {
        atomicAdd(&cnt[g], 1.f);
    }
}

__global__ void k_fill(const int* __restrict__ ei, int* __restrict__ cursor,
                       int* __restrict__ csr_src)
{
    int e = blockIdx.x * 256 + threadIdx.x;
    if (e >= EA) return;
    int s, d; edge_sd(ei, e, s, d);
    int pos = atomicAdd(&cursor[d], 1);
    csr_src[pos] = s;
}

// ---------- conv1 GEMM: W column per-lane in VGPRs, x via LDS broadcast ----------
// xp1 layout: [row][c=0..63][h=0..3] fp32 (interleaved -> 16B/lane gathers in aggr1)
__global__ __launch_bounds__(256) void k_gemm1(const float* __restrict__ x,
        const float* __restrict__ W1, const float* __restrict__ a1s_g,
        const float* __restrict__ a1d_g, float* __restrict__ xp1,
        float* __restrict__ e1s, float* __restrict__ e1d)
{
    __shared__ float sx[64 * 64];   // 16 KB: 64 rows of x
    const int t = threadIdx.x;
    const int lane = t & 63;
    const int h = __builtin_amdgcn_readfirstlane(t >> 6);
    const int row0 = blockIdx.x * 64;
    for (int i = t; i < 64 * 64; i += 256) {
        int r = row0 + (i >> 6);
        sx[i] = (r < N_NODES) ? x[(size_t)r * 64 + (i & 63)] : 0.f;
    }
    float wr[64];
    #pragma unroll
    for (int k = 0; k < 64; ++k) wr[k] = W1[k * 256 + h * 64 + lane];
    const float asv = a1s_g[h * 64 + lane];
    const float adv = a1d_g[h * 64 + lane];
    __syncthreads();
    for (int r = 0; r < 64; ++r) {
        int row = row0 + r;
        if (row >= N_NODES) break;
        float acc = 0.f;
        #pragma unroll
        for (int kq = 0; kq < 16; ++kq) {
            float4 xv = *(const float4*)&sx[r * 64 + kq * 4];
            acc = fmaf(xv.x, wr[kq * 4 + 0], acc);
            acc = fmaf(xv.y, wr[kq * 4 + 1], acc);
            acc = fmaf(xv.z, wr[kq * 4 + 2], acc);
            acc = fmaf(xv.w, wr[kq * 4 + 3], acc);
        }
        xp1[(size_t)row * 256 + lane * 4 + h] = acc;
        float ps = acc * asv, pd = acc * adv;
        #pragma unroll
        for (int off = 32; off > 0; off >>= 1) {
            ps += __shfl_down(ps, off, 64);
            pd += __shfl_down(pd, off, 64);
        }
        if (lane == 0) { e1s[row * 4 + h] = ps; e1d[row * 4 + h] = pd; }
    }
}

// ---------- attention 1: single pass, no max (scores bounded), defer 1/sum ----------
__global__ void k_att1(const int* __restrict__ rowptr, const int* __restrict__ csr_src,
                       const float* __restrict__ e1s, const float* __restrict__ e1d,
                       float* __restrict__ alpha1, float* __restrict__ rinv1)
{
    int d = blockIdx.x * 256 + threadIdx.x;
    if (d >= N_NODES) return;
    int beg = rowptr[d], end = rowptr[d + 1];
    float4 ed = ((const float4*)e1d)[d];
    float4 sum = make_float4(0.f, 0.f, 0.f, 0.f);
    for (int j = beg; j < end; ++j) {
        int s = csr_src[j];
        float4 q = ((const float4*)e1s)[s];
        float4 p;
        p.x = __expf(lrelu(q.x + ed.x));
        p.y = __expf(lrelu(q.y + ed.y));
        p.z = __expf(lrelu(q.z + ed.z));
        p.w = __expf(lrelu(q.w + ed.w));
        sum.x += p.x; sum.y += p.y; sum.z += p.z; sum.w += p.w;
        ((float4*)alpha1)[j] = p;
    }
    ((float4*)rinv1)[d] = make_float4(1.f / sum.x, 1.f / sum.y, 1.f / sum.z, 1.f / sum.w);
}

// ---------- aggr1: wave per dst, coalesced fp32 gather, fused bias+ELU -> h1 ----------
__global__ __launch_bounds__(256) void k_aggr1(const int* __restrict__ rowptr,
        const int* __restrict__ csr_src, const float* __restrict__ alpha1,
        const float* __restrict__ rinv1, const float* __restrict__ xp1,
        const float* __restrict__ b1, float* __restrict__ h1)
{
    const int lane = threadIdx.x & 63;
    const int w = __builtin_amdgcn_readfirstlane(threadIdx.x >> 6);
    const int d = blockIdx.x * 4 + w;
    if (d >= N_NODES) return;
    const int beg = rowptr[d], end = rowptr[d + 1];
    float a0 = 0.f, a1 = 0.f, a2 = 0.f, a3 = 0.f;
    #pragma unroll 2
    for (int j = beg; j < end; ++j) {
        int s = csr_src[j];
        float4 al = ((const float4*)alpha1)[j];
        float4 xv = *(const float4*)(xp1 + (size_t)s * 256 + lane * 4);
        a0 = fmaf(al.x, xv.x, a0);
        a1 = fmaf(al.y, xv.y, a1);
        a2 = fmaf(al.z, xv.z, a2);
        a3 = fmaf(al.w, xv.w, a3);
    }
    float4 iv = ((const float4*)rinv1)[d];
    float acc[4] = {a0 * iv.x, a1 * iv.y, a2 * iv.z, a3 * iv.w};
    float* hd = h1 + (size_t)d * 256;
    #pragma unroll
    for (int hh = 0; hh < 4; ++hh) {
        float v = acc[hh] + b1[hh * 64 + lane];
        hd[hh * 64 + lane] = v > 0.f ? v : __expf(v) - 1.f;
    }
}

// ---------- conv2 GEMM: K split across 4 waves, W2 chunk in VGPRs ----------
#define G2R 16
__global__ __launch_bounds__(256) void k_gemm2(const float* __restrict__ h1,
        const float* __restrict__ W2, const float* __restrict__ a2s_g,
        const float* __restrict__ a2d_g, float* __restrict__ xp2,
        float* __restrict__ e2s, float* __restrict__ e2d)
{
    __shared__ float sh[G2R * 256];        // 16 KB staged h rows
    __shared__ float sp[4 * G2R * 64];     // 16 KB partials
    const int t = threadIdx.x;
    const int lane = t & 63;
    const int w = __builtin_amdgcn_readfirstlane(t >> 6);
    float wr[64];
    #pragma unroll
    for (int k = 0; k < 64; ++k) wr[k] = W2[(size_t)(w * 64 + k) * 64 + lane];
    const float asv = a2s_g[lane], adv = a2d_g[lane];
    const int row0 = blockIdx.x * G2R;
    for (int i = t; i < G2R * 256; i += 256) {
        int r = row0 + (i >> 8);
        sh[i] = (r < N_NODES) ? h1[(size_t)r * 256 + (i & 255)] : 0.f;
    }
    __syncthreads();
    for (int r = 0; r < G2R; ++r) {
        float acc = 0.f;
        #pragma unroll
        for (int kq = 0; kq < 16; ++kq) {
            float4 xv = *(const float4*)&sh[r * 256 + w * 64 + kq * 4];
            acc = fmaf(xv.x, wr[kq * 4 + 0], acc);
            acc = fmaf(xv.y, wr[kq * 4 + 1], acc);
            acc = fmaf(xv.z, wr[kq * 4 + 2], acc);
            acc = fmaf(xv.w, wr[kq * 4 + 3], acc);
        }
        sp[(w * G2R + r) * 64 + lane] = acc;
    }
    __syncthreads();
    for (int r = w; r < G2R; r += 4) {
        int row = row0 + r;
        if (row >= N_NODES) continue;
        float acc = sp[(0 * G2R + r) * 64 + lane] + sp[(1 * G2R + r) * 64 + lane]
                  + sp[(2 * G2R + r) * 64 + lane] + sp[(3 * G2R + r) * 64 + lane];
        xp2[(size_t)row * 64 + lane] = acc;
        float ps = acc * asv, pd = acc * adv;
        #pragma unroll
        for (int off = 32; off > 0; off >>= 1) {
            ps += __shfl_down(ps, off, 64);
            pd += __shfl_down(pd, off, 64);
        }
        if (lane == 0) { e2s[row] = ps; e2d[row] = pd; }
    }
}

// ---------- attention 2: single pass, no max, defer 1/sum ----------
__global__ void k_att2(const int* __restrict__ rowptr, const int* __restrict__ csr_src,
                       const float* __restrict__ e2s, const float* __restrict__ e2d,
                       float* __restrict__ alpha2, float* __restrict__ rinv2)
{
    int d = blockIdx.x * 256 + threadIdx.x;
    if (d >= N_NODES) return;
    int beg = rowptr[d], end = rowptr[d + 1];
    float ed = e2d[d];
    float sum = 0.f;
    for (int j = beg; j < end; ++j) {
        float p = __expf(lrelu(e2s[csr_src[j]] + ed));
        sum += p;
        alpha2[j] = p;
    }
    rinv2[d] = 1.f / sum;
}

// ---------- aggr2: wave per dst, fp32 gather, fused mean-pool ----------
__global__ __launch_bounds__(256) void k_aggr2(const int* __restrict__ rowptr,
        const int* __restrict__ csr_src, const float* __restrict__ alpha2,
        const float* __restrict__ rinv2, const float* __restrict__ xp2,
        const float* __restrict__ b2, const int* __restrict__ batch,
        float* __restrict__ pooled)
{
    const int lane = threadIdx.x & 63;
    const int w = __builtin_amdgcn_readfirstlane(threadIdx.x >> 6);
    const int d = blockIdx.x * 4 + w;
    if (d >= N_NODES) return;
    const int beg = rowptr[d], end = rowptr[d + 1];
    float acc = 0.f;
    #pragma unroll 2
    for (int j = beg; j < end; ++j) {
        int s = csr_src[j];
        float al = alpha2[j];
        acc = fmaf(al, xp2[(size_t)s * 64 + lane], acc);
    }
    float val = acc * rinv2[d] + b2[lane];
    int g = batch[d];
    atomicAdd(&pooled[g * 64 + lane], val);
}

__global__ void k_mlp(const float* __restrict__ pooled, const float* __restrict__ cnt,
                      const float* __restrict__ Wh1, const float* __restrict__ bh1,
                      const float* __restrict__ Wh2, const float* __restrict__ bh2,
                      float* __restrict__ out)
{
    int g = threadIdx.x;   // 64 threads
    float inv = 1.f / fmaxf(cnt[g], 1.f);
    float p[64];
    #pragma unroll
    for (int c = 0; c < 64; ++c) p[c] = pooled[g * 64 + c] * inv;
    float acc2 = bh2[0];
    for (int j = 0; j < 16; ++j) {
        float z = bh1[j];
        #pragma unroll
        for (int c = 0; c < 64; ++c) z = fmaf(p[c], Wh1[c * 16 + j], z);
        z = fmaxf(z, 0.f);
        acc2 = fmaf(z, Wh2[j], acc2);
    }
    out[g] = 1.f / (1.f + expf(-acc2));
}

extern "C" void kernel_launch(void* const* d_in, const int* in_sizes, int n_in,
                              void* d_out, int out_size, void* d_ws, size_t ws_size,
                              hipStream_t stream)
{
    const float* x      = (const float*)d_in[0];
    const int*   ei     = (const int*)d_in[1];
    const int*   batch  = (const int*)d_in[2];
    const float* W1     = (const float*)d_in[3];
    const float* a1s    = (const float*)d_in[4];
    const float* a1d    = (const float*)d_in[5];
    const float* b1     = (const float*)d_in[6];
    const float* W2     = (const float*)d_in[7];
    const float* a2s    = (const float*)d_in[8];
    const float* a2d    = (const float*)d_in[9];
    const float* b2     = (const float*)d_in[10];
    const float* Wh1    = (const float*)d_in[11];
    const float* bh1    = (const float*)d_in[12];
    const float* Wh2    = (const float*)d_in[13];
    const float* bh2    = (const float*)d_in[14];
    float* out = (float*)d_out;

    float* ws = (float*)d_ws;
    float* xp1    = ws;                                  // N*256
    float* h1     = xp1 + (size_t)N_NODES * 256;         // N*256
    float* e1s    = h1 + (size_t)N_NODES * 256;          // N*4
    float* e1d    = e1s + (size_t)N_NODES * 4;           // N*4
    float* rinv1  = e1d + (size_t)N_NODES * 4;           // N*4
    float* alpha1 = rinv1 + (size_t)N_NODES * 4;         // EA*4
    float* e2s    = alpha1 + (size_t)EA * 4;             // N
    float* e2d    = e2s + N_NODES;                       // N
    float* rinv2  = e2d + N_NODES;                       // N
    float* alpha2 = rinv2 + N_NODES;                     // EA
    float* xp2    = alpha2 + EA;                         // N*64
    float* pooled = xp2 + (size_t)N_NODES * 64;          // 4096
    float* cnt    = pooled + NG * HID;                   // 64
    int* rowptr   = (int*)(cnt + NG);                    // N+1
    int* cursor   = rowptr + N_NODES + 1;                // N
    int* csr_src  = cursor + N_NODES;                    // EA
    int* blksum   = csr_src + EA;                        // NBLK
    int* blkoff   = blksum + NBLK;                       // NBLK
    // deg/incl alias alpha1 region (dead until k_att1; CSR build done by then)
    int* deg  = (int*)alpha1;
    int* incl = deg + N_NODES;

    const int BE = (EA + 255) / 256;
    const int BN = (N_NODES + 255) / 256;

    hipLaunchKernelGGL(k_zero,  dim3(64),   dim3(256),  0, stream, deg, pooled, cnt);
    hipLaunchKernelGGL(k_deg,   dim3(BE),   dim3(256),  0, stream, ei, deg);
    hipLaunchKernelGGL(k_scan1, dim3(NBLK), dim3(1024), 0, stream, deg, incl, blksum);
    hipLaunchKernelGGL(k_scan2, dim3(1),    dim3(64),   0, stream, blksum, blkoff);
    hipLaunchKernelGGL(k_scan3, dim3(BN),   dim3(256),  0, stream,
                       incl, blkoff, deg, batch, rowptr, cursor, cnt);
    hipLaunchKernelGGL(k_fill,  dim3(BE),   dim3(256),  0, stream, ei, cursor, csr_src);

    hipLaunchKernelGGL(k_gemm1, dim3((N_NODES + 63) / 64), dim3(256), 0, stream,
                       x, W1, a1s, a1d, xp1, e1s, e1d);
    hipLaunchKernelGGL(k_att1,  dim3(BN), dim3(256), 0, stream,
                       rowptr, csr_src, e1s, e1d, alpha1, rinv1);
    hipLaunchKernelGGL(k_aggr1, dim3((N_NODES + 3) / 4), dim3(256), 0, stream,
                       rowptr, csr_src, alpha1, rinv1, xp1, b1, h1);

    hipLaunchKernelGGL(k_gemm2, dim3((N_NODES + G2R - 1) / G2R), dim3(256), 0, stream,
                       h1, W2, a2s, a2d, xp2, e2s, e2d);
    hipLaunchKernelGGL(k_att2,  dim3(BN), dim3(256), 0, stream,
                       rowptr, csr_src, e2s, e2d, alpha2, rinv2);
    hipLaunchKernelGGL(k_aggr2, dim3((N_NODES + 3) / 4), dim3(256), 0, stream,
                       rowptr, csr_src, alpha2, rinv2, xp2, b2, batch, pooled);

    hipLaunchKernelGGL(k_mlp, dim3(1), dim3(64), 0, stream,
                       pooled, cnt, Wh1, bh1, Wh2, bh2, out);
}

// Round 5
// 546.527 us; speedup vs baseline: 3.6212x; 1.1196x over previous
//
#include <hip/hip_runtime.h>
#include <math.h>

#define N_NODES 50000
#define N_EDGES 800000
#define EA (N_EDGES + N_NODES)   /* edges + self loops = 850000 */
#define HEADS 4
#define HID 64
#define NG 64
#define NEG_SLOPE 0.2f
#define SCAN_CHUNK 1024
#define NBLK ((N_NODES + SCAN_CHUNK - 1) / SCAN_CHUNK)   /* 49 */

__device__ inline float lrelu(float x) { return x > 0.f ? x : NEG_SLOPE * x; }

__device__ inline void edge_sd(const int* __restrict__ ei, int e, int& s, int& d) {
    if (e < N_EDGES) { s = ei[e]; d = ei[N_EDGES + e]; }
    else { s = e - N_EDGES; d = s; }
}

struct h4 { _Float16 a, b, c, d; };   // 8-byte packed fp16 quad

// ---------------- CSR build ----------------
__global__ void k_zero(int* __restrict__ deg, float* __restrict__ pooled,
                       float* __restrict__ cnt)
{
    int i = blockIdx.x * 256 + threadIdx.x;
    int st = gridDim.x * 256;
    for (int j = i; j < N_NODES; j += st) deg[j] = 0;
    if (i < NG * HID) pooled[i] = 0.f;
    if (i < NG) cnt[i] = 0.f;
}

__global__ void k_deg(const int* __restrict__ ei, int* __restrict__ deg)
{
    int e = blockIdx.x * 256 + threadIdx.x;
    if (e >= EA) return;
    int s, d; edge_sd(ei, e, s, d);
    atomicAdd(&deg[d], 1);
}

__global__ __launch_bounds__(1024) void k_scan1(const int* __restrict__ deg,
        int* __restrict__ incl, int* __restrict__ blksum)
{
    __shared__ int sd[SCAN_CHUNK];
    int t = threadIdx.x;
    int i = blockIdx.x * SCAN_CHUNK + t;
    sd[t] = (i < N_NODES) ? deg[i] : 0;
    for (int off = 1; off < SCAN_CHUNK; off <<= 1) {
        __syncthreads();
        int u = (t >= off) ? sd[t - off] : 0;
        __syncthreads();
        sd[t] += u;
    }
    if (i < N_NODES) incl[i] = sd[t];
    if (t == SCAN_CHUNK - 1) blksum[blockIdx.x] = sd[t];
}

__global__ void k_scan2(const int* __restrict__ blksum, int* __restrict__ blkoff)
{
    if (threadIdx.x == 0) {
        int acc = 0;
        for (int b = 0; b < NBLK; ++b) { blkoff[b] = acc; acc += blksum[b]; }
    }
}

__global__ void k_scan3(const int* __restrict__ incl, const int* __restrict__ blkoff,
                        const int* __restrict__ deg, const int* __restrict__ batch,
                        int* __restrict__ rowptr, int* __restrict__ cursor,
                        float* __restrict__ cnt)
{
    int i = blockIdx.x * 256 + threadIdx.x;
    bool act = i < N_NODES;
    if (act) {
        int v = incl[i] + blkoff[i >> 10];
        rowptr[i + 1] = v;
        cursor[i] = v - deg[i];
        if (i == 0) rowptr[0] = 0;
    }
    int g = act ? batch[i] : -1;
    int lane = threadIdx.x & 63;
    int g0 = __shfl(g, 0, 64);
    if (__all(g == g0)) {
        if (lane == 0 && g0 >= 0) atomicAdd(&cnt[g0], 64.f);
    } else if (act) {
        atomicAdd(&cnt[g], 1.f);
    }
}

__global__ void k_fill(const int* __restrict__ ei, int* __restrict__ cursor,
                       int* __restrict__ csr_src)
{
    int e = blockIdx.x * 256 + threadIdx.x;
    if (e >= EA) return;
    int s, d; edge_sd(ei, e, s, d);
    int pos = atomicAdd(&cursor[d], 1);
    csr_src[pos] = s;
}

// ---------- conv1 GEMM: W column per-lane in VGPRs, x via LDS broadcast ----------
// xp1h layout: [row][c=0..63][h=0..3] fp16 (interleaved -> 8B/lane gathers in aggr1)
__global__ __launch_bounds__(256) void k_gemm1(const float* __restrict__ x,
        const float* __restrict__ W1, const float* __restrict__ a1s_g,
        const float* __restrict__ a1d_g, _Float16* __restrict__ xp1h,
        float* __restrict__ e1s, float* __restrict__ e1d)
{
    __shared__ float sx[64 * 64];   // 16 KB: 64 rows of x
    const int t = threadIdx.x;
    const int lane = t & 63;
    const int h = __builtin_amdgcn_readfirstlane(t >> 6);
    const int row0 = blockIdx.x * 64;
    for (int i = t; i < 64 * 64; i += 256) {
        int r = row0 + (i >> 6);
        sx[i] = (r < N_NODES) ? x[(size_t)r * 64 + (i & 63)] : 0.f;
    }
    float wr[64];
    #pragma unroll
    for (int k = 0; k < 64; ++k) wr[k] = W1[k * 256 + h * 64 + lane];
    const float asv = a1s_g[h * 64 + lane];
    const float adv = a1d_g[h * 64 + lane];
    __syncthreads();
    for (int r = 0; r < 64; ++r) {
        int row = row0 + r;
        if (row >= N_NODES) break;
        float acc = 0.f;
        #pragma unroll
        for (int kq = 0; kq < 16; ++kq) {
            float4 xv = *(const float4*)&sx[r * 64 + kq * 4];
            acc = fmaf(xv.x, wr[kq * 4 + 0], acc);
            acc = fmaf(xv.y, wr[kq * 4 + 1], acc);
            acc = fmaf(xv.z, wr[kq * 4 + 2], acc);
            acc = fmaf(xv.w, wr[kq * 4 + 3], acc);
        }
        xp1h[(size_t)row * 256 + lane * 4 + h] = (_Float16)acc;
        float ps = acc * asv, pd = acc * adv;
        #pragma unroll
        for (int off = 32; off > 0; off >>= 1) {
            ps += __shfl_down(ps, off, 64);
            pd += __shfl_down(pd, off, 64);
        }
        if (lane == 0) { e1s[row * 4 + h] = ps; e1d[row * 4 + h] = pd; }
    }
}

// ---------- attention 1: single pass, no max (scores bounded), defer 1/sum ----------
__global__ void k_att1(const int* __restrict__ rowptr, const int* __restrict__ csr_src,
                       const float* __restrict__ e1s, const float* __restrict__ e1d,
                       float* __restrict__ alpha1, float* __restrict__ rinv1)
{
    int d = blockIdx.x * 256 + threadIdx.x;
    if (d >= N_NODES) return;
    int beg = rowptr[d], end = rowptr[d + 1];
    float4 ed = ((const float4*)e1d)[d];
    float4 sum = make_float4(0.f, 0.f, 0.f, 0.f);
    for (int j = beg; j < end; ++j) {
        int s = csr_src[j];
        float4 q = ((const float4*)e1s)[s];
        float4 p;
        p.x = __expf(lrelu(q.x + ed.x));
        p.y = __expf(lrelu(q.y + ed.y));
        p.z = __expf(lrelu(q.z + ed.z));
        p.w = __expf(lrelu(q.w + ed.w));
        sum.x += p.x; sum.y += p.y; sum.z += p.z; sum.w += p.w;
        ((float4*)alpha1)[j] = p;
    }
    ((float4*)rinv1)[d] = make_float4(1.f / sum.x, 1.f / sum.y, 1.f / sum.z, 1.f / sum.w);
}

// ---------- aggr1: wave per dst, 8B/lane fp16 gather, fused bias+ELU -> h1 ----------
__global__ __launch_bounds__(256) void k_aggr1(const int* __restrict__ rowptr,
        const int* __restrict__ csr_src, const float* __restrict__ alpha1,
        const float* __restrict__ rinv1, const _Float16* __restrict__ xp1h,
        const float* __restrict__ b1, float* __restrict__ h1)
{
    const int lane = threadIdx.x & 63;
    const int w = __builtin_amdgcn_readfirstlane(threadIdx.x >> 6);
    const int d = blockIdx.x * 4 + w;
    if (d >= N_NODES) return;
    const int beg = rowptr[d], end = rowptr[d + 1];
    float a0 = 0.f, a1 = 0.f, a2 = 0.f, a3 = 0.f;
    #pragma unroll 2
    for (int j = beg; j < end; ++j) {
        int s = csr_src[j];
        float4 al = ((const float4*)alpha1)[j];
        h4 xv = *(const h4*)(xp1h + (size_t)s * 256 + lane * 4);
        a0 = fmaf(al.x, (float)xv.a, a0);
        a1 = fmaf(al.y, (float)xv.b, a1);
        a2 = fmaf(al.z, (float)xv.c, a2);
        a3 = fmaf(al.w, (float)xv.d, a3);
    }
    float4 iv = ((const float4*)rinv1)[d];
    float acc[4] = {a0 * iv.x, a1 * iv.y, a2 * iv.z, a3 * iv.w};
    float* hd = h1 + (size_t)d * 256;
    #pragma unroll
    for (int hh = 0; hh < 4; ++hh) {
        float v = acc[hh] + b1[hh * 64 + lane];
        hd[hh * 64 + lane] = v > 0.f ? v : __expf(v) - 1.f;
    }
}

// ---------- conv2 GEMM: K split across 4 waves, W2 chunk in VGPRs ----------
#define G2R 16
__global__ __launch_bounds__(256) void k_gemm2(const float* __restrict__ h1,
        const float* __restrict__ W2, const float* __restrict__ a2s_g,
        const float* __restrict__ a2d_g, _Float16* __restrict__ xp2h,
        float* __restrict__ e2s, float* __restrict__ e2d)
{
    __shared__ float sh[G2R * 256];        // 16 KB staged h rows
    __shared__ float sp[4 * G2R * 64];     // 16 KB partials
    const int t = threadIdx.x;
    const int lane = t & 63;
    const int w = __builtin_amdgcn_readfirstlane(t >> 6);
    float wr[64];
    #pragma unroll
    for (int k = 0; k < 64; ++k) wr[k] = W2[(size_t)(w * 64 + k) * 64 + lane];
    const float asv = a2s_g[lane], adv = a2d_g[lane];
    const int row0 = blockIdx.x * G2R;
    for (int i = t; i < G2R * 256; i += 256) {
        int r = row0 + (i >> 8);
        sh[i] = (r < N_NODES) ? h1[(size_t)r * 256 + (i & 255)] : 0.f;
    }
    __syncthreads();
    for (int r = 0; r < G2R; ++r) {
        float acc = 0.f;
        #pragma unroll
        for (int kq = 0; kq < 16; ++kq) {
            float4 xv = *(const float4*)&sh[r * 256 + w * 64 + kq * 4];
            acc = fmaf(xv.x, wr[kq * 4 + 0], acc);
            acc = fmaf(xv.y, wr[kq * 4 + 1], acc);
            acc = fmaf(xv.z, wr[kq * 4 + 2], acc);
            acc = fmaf(xv.w, wr[kq * 4 + 3], acc);
        }
        sp[(w * G2R + r) * 64 + lane] = acc;
    }
    __syncthreads();
    for (int r = w; r < G2R; r += 4) {
        int row = row0 + r;
        if (row >= N_NODES) continue;
        float acc = sp[(0 * G2R + r) * 64 + lane] + sp[(1 * G2R + r) * 64 + lane]
                  + sp[(2 * G2R + r) * 64 + lane] + sp[(3 * G2R + r) * 64 + lane];
        xp2h[(size_t)row * 64 + lane] = (_Float16)acc;
        float ps = acc * asv, pd = acc * adv;
        #pragma unroll
        for (int off = 32; off > 0; off >>= 1) {
            ps += __shfl_down(ps, off, 64);
            pd += __shfl_down(pd, off, 64);
        }
        if (lane == 0) { e2s[row] = ps; e2d[row] = pd; }
    }
}

// ---------- attention 2: single pass, no max, defer 1/sum ----------
__global__ void k_att2(const int* __restrict__ rowptr, const int* __restrict__ csr_src,
                       const float* __restrict__ e2s, const float* __restrict__ e2d,
                       float* __restrict__ alpha2, float* __restrict__ rinv2)
{
    int d = blockIdx.x * 256 + threadIdx.x;
    if (d >= N_NODES) return;
    int beg = rowptr[d], end = rowptr[d + 1];
    float ed = e2d[d];
    float sum = 0.f;
    for (int j = beg; j < end; ++j) {
        float p = __expf(lrelu(e2s[csr_src[j]] + ed));
        sum += p;
        alpha2[j] = p;
    }
    rinv2[d] = 1.f / sum;
}

// ---------- aggr2: wave per dst, fp16 gather, fused mean-pool ----------
__global__ __launch_bounds__(256) void k_aggr2(const int* __restrict__ rowptr,
        const int* __restrict__ csr_src, const float* __restrict__ alpha2,
        const float* __restrict__ rinv2, const _Float16* __restrict__ xp2h,
        const float* __restrict__ b2, const int* __restrict__ batch,
        float* __restrict__ pooled)
{
    const int lane = threadIdx.x & 63;
    const int w = __builtin_amdgcn_readfirstlane(threadIdx.x >> 6);
    const int d = blockIdx.x * 4 + w;
    if (d >= N_NODES) return;
    const int beg = rowptr[d], end = rowptr[d + 1];
    float acc = 0.f;
    #pragma unroll 2
    for (int j = beg; j < end; ++j) {
        int s = csr_src[j];
        float al = alpha2[j];
        acc = fmaf(al, (float)xp2h[(size_t)s * 64 + lane], acc);
    }
    float val = acc * rinv2[d] + b2[lane];
    int g = batch[d];
    atomicAdd(&pooled[g * 64 + lane], val);
}

__global__ void k_mlp(const float* __restrict__ pooled, const float* __restrict__ cnt,
                      const float* __restrict__ Wh1, const float* __restrict__ bh1,
                      const float* __restrict__ Wh2, const float* __restrict__ bh2,
                      float* __restrict__ out)
{
    int g = threadIdx.x;   // 64 threads
    float inv = 1.f / fmaxf(cnt[g], 1.f);
    float p[64];
    #pragma unroll
    for (int c = 0; c < 64; ++c) p[c] = pooled[g * 64 + c] * inv;
    float acc2 = bh2[0];
    for (int j = 0; j < 16; ++j) {
        float z = bh1[j];
        #pragma unroll
        for (int c = 0; c < 64; ++c) z = fmaf(p[c], Wh1[c * 16 + j], z);
        z = fmaxf(z, 0.f);
        acc2 = fmaf(z, Wh2[j], acc2);
    }
    out[g] = 1.f / (1.f + expf(-acc2));
}

extern "C" void kernel_launch(void* const* d_in, const int* in_sizes, int n_in,
                              void* d_out, int out_size, void* d_ws, size_t ws_size,
                              hipStream_t stream)
{
    const float* x      = (const float*)d_in[0];
    const int*   ei     = (const int*)d_in[1];
    const int*   batch  = (const int*)d_in[2];
    const float* W1     = (const float*)d_in[3];
    const float* a1s    = (const float*)d_in[4];
    const float* a1d    = (const float*)d_in[5];
    const float* b1     = (const float*)d_in[6];
    const float* W2     = (const float*)d_in[7];
    const float* a2s    = (const float*)d_in[8];
    const float* a2d    = (const float*)d_in[9];
    const float* b2     = (const float*)d_in[10];
    const float* Wh1    = (const float*)d_in[11];
    const float* bh1    = (const float*)d_in[12];
    const float* Wh2    = (const float*)d_in[13];
    const float* bh2    = (const float*)d_in[14];
    float* out = (float*)d_out;

    float* ws = (float*)d_ws;
    _Float16* xp1h = (_Float16*)ws;                      // N*256 fp16 = N*128 f32
    float* h1     = ws + (size_t)N_NODES * 128;          // N*256
    float* e1s    = h1 + (size_t)N_NODES * 256;          // N*4
    float* e1d    = e1s + (size_t)N_NODES * 4;           // N*4
    float* rinv1  = e1d + (size_t)N_NODES * 4;           // N*4
    float* alpha1 = rinv1 + (size_t)N_NODES * 4;         // EA*4
    float* e2s    = alpha1 + (size_t)EA * 4;             // N
    float* e2d    = e2s + N_NODES;                       // N
    float* rinv2  = e2d + N_NODES;                       // N
    float* alpha2 = rinv2 + N_NODES;                     // EA
    _Float16* xp2h = (_Float16*)(alpha2 + EA);           // N*64 fp16 = N*32 f32
    float* pooled = alpha2 + EA + (size_t)N_NODES * 32;  // 4096
    float* cnt    = pooled + NG * HID;                   // 64
    int* rowptr   = (int*)(cnt + NG);                    // N+1
    int* cursor   = rowptr + N_NODES + 1;                // N
    int* csr_src  = cursor + N_NODES;                    // EA
    int* blksum   = csr_src + EA;                        // NBLK
    int* blkoff   = blksum + NBLK;                       // NBLK
    // deg/incl alias alpha1 region (dead until k_att1; CSR build done by then)
    int* deg  = (int*)alpha1;
    int* incl = deg + N_NODES;

    const int BE = (EA + 255) / 256;
    const int BN = (N_NODES + 255) / 256;

    hipLaunchKernelGGL(k_zero,  dim3(64),   dim3(256),  0, stream, deg, pooled, cnt);
    hipLaunchKernelGGL(k_deg,   dim3(BE),   dim3(256),  0, stream, ei, deg);
    hipLaunchKernelGGL(k_scan1, dim3(NBLK), dim3(1024), 0, stream, deg, incl, blksum);
    hipLaunchKernelGGL(k_scan2, dim3(1),    dim3(64),   0, stream, blksum, blkoff);
    hipLaunchKernelGGL(k_scan3, dim3(BN),   dim3(256),  0, stream,
                       incl, blkoff, deg, batch, rowptr, cursor, cnt);
    hipLaunchKernelGGL(k_fill,  dim3(BE),   dim3(256),  0, stream, ei, cursor, csr_src);

    hipLaunchKernelGGL(k_gemm1, dim3((N_NODES + 63) / 64), dim3(256), 0, stream,
                       x, W1, a1s, a1d, xp1h, e1s, e1d);
    hipLaunchKernelGGL(k_att1,  dim3(BN), dim3(256), 0, stream,
                       rowptr, csr_src, e1s, e1d, alpha1, rinv1);
    hipLaunchKernelGGL(k_aggr1, dim3((N_NODES + 3) / 4), dim3(256), 0, stream,
                       rowptr, csr_src, alpha1, rinv1, xp1h, b1, h1);

    hipLaunchKernelGGL(k_gemm2, dim3((N_NODES + G2R - 1) / G2R), dim3(256), 0, stream,
                       h1, W2, a2s, a2d, xp2h, e2s, e2d);
    hipLaunchKernelGGL(k_att2,  dim3(BN), dim3(256), 0, stream,
                       rowptr, csr_src, e2s, e2d, alpha2, rinv2);
    hipLaunchKernelGGL(k_aggr2, dim3((N_NODES + 3) / 4), dim3(256), 0, stream,
                       rowptr, csr_src, alpha2, rinv2, xp2h, b2, batch, pooled);

    hipLaunchKernelGGL(k_mlp, dim3(1), dim3(64), 0, stream,
                       pooled, cnt, Wh1, bh1, Wh2, bh2, out);
}

// Round 7
// 511.855 us; speedup vs baseline: 3.8665x; 1.0677x over previous
//
#include <hip/hip_runtime.h>
#include <math.h>

#define N_NODES 50000
#define N_EDGES 800000
#define EA (N_EDGES + N_NODES)   /* edges + self loops = 850000 */
#define HEADS 4
#define HID 64
#define NG 64
#define NEG_SLOPE 0.2f
#define SCAN_CHUNK 1024
#define NBLK ((N_NODES + SCAN_CHUNK - 1) / SCAN_CHUNK)   /* 49 */

typedef _Float16 f16x8 __attribute__((ext_vector_type(8)));
typedef float f32x4 __attribute__((ext_vector_type(4)));
struct h4 { _Float16 a, b, c, d; };   // 8-byte packed fp16 quad

__device__ inline float lrelu(float x) { return x > 0.f ? x : NEG_SLOPE * x; }

__device__ inline void edge_sd(const int* __restrict__ ei, int e, int& s, int& d) {
    if (e < N_EDGES) { s = ei[e]; d = ei[N_EDGES + e]; }
    else { s = e - N_EDGES; d = s; }
}

// MFMA 16x16x32 f16 operand fragment: lane l, elem j -> k = 16*(j>>2) + (l>>4)*4 + (j&3)
// (two glued 16x16x16 halves). p = row base (k contiguous), lq = lane>>4.
__device__ inline f16x8 ldfrag(const _Float16* __restrict__ p, int lq) {
    uint2 lo = *(const uint2*)(p + lq * 4);
    uint2 hi = *(const uint2*)(p + 16 + lq * 4);
    union { uint4 u; f16x8 v; } f;
    f.u = make_uint4(lo.x, lo.y, hi.x, hi.y);
    return f.v;
}

// ---------------- CSR build ----------------
__global__ void k_zero(int* __restrict__ deg, float* __restrict__ pooled,
                       float* __restrict__ cnt)
{
    int i = blockIdx.x * 256 + threadIdx.x;
    int st = gridDim.x * 256;
    for (int j = i; j < N_NODES; j += st) deg[j] = 0;
    if (i < NG * HID) pooled[i] = 0.f;
    if (i < NG) cnt[i] = 0.f;
}

__global__ void k_deg(const int* __restrict__ ei, int* __restrict__ deg)
{
    int e = blockIdx.x * 256 + threadIdx.x;
    if (e >= EA) return;
    int s, d; edge_sd(ei, e, s, d);
    atomicAdd(&deg[d], 1);
}

__global__ __launch_bounds__(1024) void k_scan1(const int* __restrict__ deg,
        int* __restrict__ incl, int* __restrict__ blksum)
{
    __shared__ int sd[SCAN_CHUNK];
    int t = threadIdx.x;
    int i = blockIdx.x * SCAN_CHUNK + t;
    sd[t] = (i < N_NODES) ? deg[i] : 0;
    for (int off = 1; off < SCAN_CHUNK; off <<= 1) {
        __syncthreads();
        int u = (t >= off) ? sd[t - off] : 0;
        __syncthreads();
        sd[t] += u;
    }
    if (i < N_NODES) incl[i] = sd[t];
    if (t == SCAN_CHUNK - 1) blksum[blockIdx.x] = sd[t];
}

__global__ void k_scan2(const int* __restrict__ blksum, int* __restrict__ blkoff)
{
    if (threadIdx.x == 0) {
        int acc = 0;
        for (int b = 0; b < NBLK; ++b) { blkoff[b] = acc; acc += blksum[b]; }
    }
}

__global__ void k_scan3(const int* __restrict__ incl, const int* __restrict__ blkoff,
                        const int* __restrict__ deg, const int* __restrict__ batch,
                        int* __restrict__ rowptr, int* __restrict__ cursor,
                        float* __restrict__ cnt)
{
    int i = blockIdx.x * 256 + threadIdx.x;
    bool act = i < N_NODES;
    if (act) {
        int v = incl[i] + blkoff[i >> 10];
        rowptr[i + 1] = v;
        cursor[i] = v - deg[i];
        if (i == 0) rowptr[0] = 0;
    }
    int g = act ? batch[i] : -1;
    int lane = threadIdx.x & 63;
    int g0 = __shfl(g, 0, 64);
    if (__all(g == g0)) {
        if (lane == 0 && g0 >= 0) atomicAdd(&cnt[g0], 64.f);
    } else if (act) {
        atomicAdd(&cnt[g], 1.f);
    }
}

__global__ void k_fill(const int* __restrict__ ei, int* __restrict__ cursor,
                       int* __restrict__ csr_src)
{
    int e = blockIdx.x * 256 + threadIdx.x;
    if (e >= EA) return;
    int s, d; edge_sd(ei, e, s, d);
    int pos = atomicAdd(&cursor[d], 1);
    csr_src[pos] = s;
}

// ---------- prep: fp16 weight permutes + score-projection vectors (1 block) ----------
// W1P[n'=c*4+h][k] = W1[k][h*64+c]   (256x64 fp16)
// W2P[n][k]        = W2[k][n]        (64x256 fp16)
// va1s[k][h] = sum_c W1[k,h*64+c] a1s[h,c]; va1d likewise    ([64][4] f32)
// va2s[k]    = sum_c W2[k,c] a2s[c];        va2d likewise    ([256] f32)
__global__ __launch_bounds__(256) void k_prepw(const float* __restrict__ W1,
        const float* __restrict__ a1s, const float* __restrict__ a1d,
        const float* __restrict__ W2, const float* __restrict__ a2s,
        const float* __restrict__ a2d, _Float16* __restrict__ W1P,
        _Float16* __restrict__ W2P, float* __restrict__ va1s,
        float* __restrict__ va1d, float* __restrict__ va2s, float* __restrict__ va2d)
{
    const int t = threadIdx.x;
    for (int i = t; i < 256 * 64; i += 256) {
        int np = i >> 6, k = i & 63;
        W1P[i] = (_Float16)W1[k * 256 + (np & 3) * 64 + (np >> 2)];
    }
    for (int i = t; i < 64 * 256; i += 256) {
        int n = i >> 8, k = i & 255;
        W2P[i] = (_Float16)W2[k * 64 + n];
    }
    {
        int k = t >> 2, h = t & 3;
        float ss = 0.f, sd = 0.f;
        for (int c = 0; c < 64; ++c) {
            float wv = W1[k * 256 + h * 64 + c];
            ss = fmaf(wv, a1s[h * 64 + c], ss);
            sd = fmaf(wv, a1d[h * 64 + c], sd);
        }
        va1s[k * 4 + h] = ss;
        va1d[k * 4 + h] = sd;
    }
    {
        float ss = 0.f, sd = 0.f;
        for (int c = 0; c < 64; ++c) {
            float wv = W2[t * 64 + c];
            ss = fmaf(wv, a2s[c], ss);
            sd = fmaf(wv, a2d[c], sd);
        }
        va2s[t] = ss;
        va2d[t] = sd;
    }
}

// ---------- prepx: wave per node: x -> fp16, fused exact fp32 conv1 scores ----------
__global__ __launch_bounds__(256) void k_prepx(const float* __restrict__ x,
        const float* __restrict__ va1s, const float* __restrict__ va1d,
        _Float16* __restrict__ xh, float* __restrict__ e1s, float* __restrict__ e1d)
{
    const int lane = threadIdx.x & 63;
    const int w = threadIdx.x >> 6;
    const int n = blockIdx.x * 4 + w;
    if (n >= N_NODES) return;
    float xv = x[(size_t)n * 64 + lane];
    xh[(size_t)n * 64 + lane] = (_Float16)xv;
    float4 vs = ((const float4*)va1s)[lane];   // va1s[k=lane][0..3]
    float4 vd = ((const float4*)va1d)[lane];
    float s0 = xv * vs.x, s1 = xv * vs.y, s2 = xv * vs.z, s3 = xv * vs.w;
    float d0 = xv * vd.x, d1 = xv * vd.y, d2 = xv * vd.z, d3 = xv * vd.w;
    #pragma unroll
    for (int off = 32; off > 0; off >>= 1) {
        s0 += __shfl_down(s0, off, 64); s1 += __shfl_down(s1, off, 64);
        s2 += __shfl_down(s2, off, 64); s3 += __shfl_down(s3, off, 64);
        d0 += __shfl_down(d0, off, 64); d1 += __shfl_down(d1, off, 64);
        d2 += __shfl_down(d2, off, 64); d3 += __shfl_down(d3, off, 64);
    }
    if (lane == 0) {
        ((float4*)e1s)[n] = make_float4(s0, s1, s2, s3);
        ((float4*)e1d)[n] = make_float4(d0, d1, d2, d3);
    }
}

// ---------- conv1 GEMM via MFMA: xp1h[m][c*4+h] = (x @ W1)[m][h*64+c] ----------
// swapped operands: D = mfma(W1P_frag, x_frag) -> lane holds 4 consecutive n' of one row m
__global__ __launch_bounds__(256) void k_gemm1(const _Float16* __restrict__ xh,
        const _Float16* __restrict__ W1P, _Float16* __restrict__ xp1h)
{
    const int t = threadIdx.x;
    const int lane = t & 63, w = t >> 6;
    const int l15 = lane & 15, lq = lane >> 4;
    const int m0 = blockIdx.x * 64 + w * 16;
    const int mrow = m0 + l15;
    const _Float16* xrow = xh + (size_t)(m0 + l15) * 64;
    f16x8 xf0 = ldfrag(xrow, lq);        // k 0..31
    f16x8 xf1 = ldfrag(xrow + 32, lq);   // k 32..63
    #pragma unroll
    for (int ct = 0; ct < 16; ++ct) {
        const _Float16* wrow = W1P + (size_t)(ct * 16 + l15) * 64;
        f16x8 wf0 = ldfrag(wrow, lq);
        f16x8 wf1 = ldfrag(wrow + 32, lq);
        f32x4 acc = {0.f, 0.f, 0.f, 0.f};
        acc = __builtin_amdgcn_mfma_f32_16x16x32_f16(wf0, xf0, acc, 0, 0, 0);
        acc = __builtin_amdgcn_mfma_f32_16x16x32_f16(wf1, xf1, acc, 0, 0, 0);
        if (mrow < N_NODES) {
            h4 o = {(_Float16)acc[0], (_Float16)acc[1], (_Float16)acc[2], (_Float16)acc[3]};
            *(h4*)(xp1h + (size_t)mrow * 256 + ct * 16 + lq * 4) = o;
        }
    }
}

// ---------- attention 1: single pass, no max (scores bounded), defer 1/sum ----------
__global__ void k_att1(const int* __restrict__ rowptr, const int* __restrict__ csr_src,
                       const float* __restrict__ e1s, const float* __restrict__ e1d,
                       float* __restrict__ alpha1, float* __restrict__ rinv1)
{
    int d = blockIdx.x * 256 + threadIdx.x;
    if (d >= N_NODES) return;
    int beg = rowptr[d], end = rowptr[d + 1];
    float4 ed = ((const float4*)e1d)[d];
    float4 sum = make_float4(0.f, 0.f, 0.f, 0.f);
    for (int j = beg; j < end; ++j) {
        int s = csr_src[j];
        float4 q = ((const float4*)e1s)[s];
        float4 p;
        p.x = __expf(lrelu(q.x + ed.x));
        p.y = __expf(lrelu(q.y + ed.y));
        p.z = __expf(lrelu(q.z + ed.z));
        p.w = __expf(lrelu(q.w + ed.w));
        sum.x += p.x; sum.y += p.y; sum.z += p.z; sum.w += p.w;
        ((float4*)alpha1)[j] = p;
    }
    ((float4*)rinv1)[d] = make_float4(1.f / sum.x, 1.f / sum.y, 1.f / sum.z, 1.f / sum.w);
}

// ---------- aggr1: wave per dst, 8B fp16 gather, fused bias+ELU + conv2 scores ----------
__global__ __launch_bounds__(256) void k_aggr1(const int* __restrict__ rowptr,
        const int* __restrict__ csr_src, const float* __restrict__ alpha1,
        const float* __restrict__ rinv1, const _Float16* __restrict__ xp1h,
        const float* __restrict__ b1, const float* __restrict__ va2s,
        const float* __restrict__ va2d, _Float16* __restrict__ h1h,
        float* __restrict__ e2s, float* __restrict__ e2d)
{
    const int lane = threadIdx.x & 63;
    const int w = __builtin_amdgcn_readfirstlane(threadIdx.x >> 6);
    const int d = blockIdx.x * 4 + w;
    if (d >= N_NODES) return;
    const int beg = rowptr[d], end = rowptr[d + 1];
    float a0 = 0.f, a1 = 0.f, a2 = 0.f, a3 = 0.f;
    #pragma unroll 2
    for (int j = beg; j < end; ++j) {
        int s = csr_src[j];
        float4 al = ((const float4*)alpha1)[j];
        h4 xv = *(const h4*)(xp1h + (size_t)s * 256 + lane * 4);
        a0 = fmaf(al.x, (float)xv.a, a0);
        a1 = fmaf(al.y, (float)xv.b, a1);
        a2 = fmaf(al.z, (float)xv.c, a2);
        a3 = fmaf(al.w, (float)xv.d, a3);
    }
    float4 iv = ((const float4*)rinv1)[d];
    float acc[4] = {a0 * iv.x, a1 * iv.y, a2 * iv.z, a3 * iv.w};
    float es = 0.f, edd = 0.f;
    #pragma unroll
    for (int hh = 0; hh < 4; ++hh) {
        float v = acc[hh] + b1[hh * 64 + lane];
        v = v > 0.f ? v : __expf(v) - 1.f;
        h1h[(size_t)d * 256 + hh * 64 + lane] = (_Float16)v;
        es  = fmaf(v, va2s[hh * 64 + lane], es);
        edd = fmaf(v, va2d[hh * 64 + lane], edd);
    }
    #pragma unroll
    for (int off = 32; off > 0; off >>= 1) {
        es += __shfl_down(es, off, 64);
        edd += __shfl_down(edd, off, 64);
    }
    if (lane == 0) { e2s[d] = es; e2d[d] = edd; }
}

// ---------- conv2 GEMM via MFMA: xp2h[m][n] = (h1 @ W2)[m][n] ----------
__global__ __launch_bounds__(256) void k_gemm2(const _Float16* __restrict__ h1h,
        const _Float16* __restrict__ W2P, _Float16* __restrict__ xp2h)
{
    const int t = threadIdx.x;
    const int lane = t & 63, w = t >> 6;
    const int l15 = lane & 15, lq = lane >> 4;
    const int m0 = blockIdx.x * 64 + w * 16;
    const int mrow = m0 + l15;
    const _Float16* arow = h1h + (size_t)(m0 + l15) * 256;
    f16x8 af[8];
    #pragma unroll
    for (int ks = 0; ks < 8; ++ks) af[ks] = ldfrag(arow + ks * 32, lq);
    #pragma unroll
    for (int ct = 0; ct < 4; ++ct) {
        const _Float16* wrow = W2P + (size_t)(ct * 16 + l15) * 256;
        f32x4 acc = {0.f, 0.f, 0.f, 0.f};
        #pragma unroll
        for (int ks = 0; ks < 8; ++ks) {
            f16x8 wf = ldfrag(wrow + ks * 32, lq);
            acc = __builtin_amdgcn_mfma_f32_16x16x32_f16(wf, af[ks], acc, 0, 0, 0);
        }
        if (mrow < N_NODES) {
            h4 o = {(_Float16)acc[0], (_Float16)acc[1], (_Float16)acc[2], (_Float16)acc[3]};
            *(h4*)(xp2h + (size_t)mrow * 64 + ct * 16 + lq * 4) = o;
        }
    }
}

// ---------- attention 2: single pass, no max, defer 1/sum ----------
__global__ void k_att2(const int* __restrict__ rowptr, const int* __restrict__ csr_src,
                       const float* __restrict__ e2s, const float* __restrict__ e2d,
                       float* __restrict__ alpha2, float* __restrict__ rinv2)
{
    int d = blockIdx.x * 256 + threadIdx.x;
    if (d >= N_NODES) return;
    int beg = rowptr[d], end = rowptr[d + 1];
    float ed = e2d[d];
    float sum = 0.f;
    for (int j = beg; j < end; ++j) {
        float p = __expf(lrelu(e2s[csr_src[j]] + ed));
        sum += p;
        alpha2[j] = p;
    }
    rinv2[d] = 1.f / sum;
}

// ---------- aggr2: wave per dst, fp16 gather, fused mean-pool ----------
__global__ __launch_bounds__(256) void k_aggr2(const int* __restrict__ rowptr,
        const int* __restrict__ csr_src, const float* __restrict__ alpha2,
        const float* __restrict__ rinv2, const _Float16* __restrict__ xp2h,
        const float* __restrict__ b2, const int* __restrict__ batch,
        float* __restrict__ pooled)
{
    const int lane = threadIdx.x & 63;
    const int w = __builtin_amdgcn_readfirstlane(threadIdx.x >> 6);
    const int d = blockIdx.x * 4 + w;
    if (d >= N_NODES) return;
    const int beg = rowptr[d], end = rowptr[d + 1];
    float acc = 0.f;
    #pragma unroll 2
    for (int j = beg; j < end; ++j) {
        int s = csr_src[j];
        float al = alpha2[j];
        acc = fmaf(al, (float)xp2h[(size_t)s * 64 + lane], acc);
    }
    float val = acc * rinv2[d] + b2[lane];
    int g = batch[d];
    atomicAdd(&pooled[g * 64 + lane], val);
}

__global__ void k_mlp(const float* __restrict__ pooled, const float* __restrict__ cnt,
                      const float* __restrict__ Wh1, const float* __restrict__ bh1,
                      const float* __restrict__ Wh2, const float* __restrict__ bh2,
                      float* __restrict__ out)
{
    int g = threadIdx.x;   // 64 threads
    float inv = 1.f / fmaxf(cnt[g], 1.f);
    float p[64];
    #pragma unroll
    for (int c = 0; c < 64; ++c) p[c] = pooled[g * 64 + c] * inv;
    float acc2 = bh2[0];
    for (int j = 0; j < 16; ++j) {
        float z = bh1[j];
        #pragma unroll
        for (int c = 0; c < 64; ++c) z = fmaf(p[c], Wh1[c * 16 + j], z);
        z = fmaxf(z, 0.f);
        acc2 = fmaf(z, Wh2[j], acc2);
    }
    out[g] = 1.f / (1.f + expf(-acc2));
}

extern "C" void kernel_launch(void* const* d_in, const int* in_sizes, int n_in,
                              void* d_out, int out_size, void* d_ws, size_t ws_size,
                              hipStream_t stream)
{
    const float* x      = (const float*)d_in[0];
    const int*   ei     = (const int*)d_in[1];
    const int*   batch  = (const int*)d_in[2];
    const float* W1     = (const float*)d_in[3];
    const float* a1s    = (const float*)d_in[4];
    const float* a1d    = (const float*)d_in[5];
    const float* b1     = (const float*)d_in[6];
    const float* W2     = (const float*)d_in[7];
    const float* a2s    = (const float*)d_in[8];
    const float* a2d    = (const float*)d_in[9];
    const float* b2     = (const float*)d_in[10];
    const float* Wh1    = (const float*)d_in[11];
    const float* bh1    = (const float*)d_in[12];
    const float* Wh2    = (const float*)d_in[13];
    const float* bh2    = (const float*)d_in[14];
    float* out = (float*)d_out;

    float* ws = (float*)d_ws;
    size_t off = 0;
    _Float16* xp1h = (_Float16*)(ws + off); off += (size_t)N_NODES * 128;        // N*256 fp16
    _Float16* h1h  = (_Float16*)(ws + off); off += (size_t)(N_NODES + 64) * 128; // padded
    _Float16* xh   = (_Float16*)(ws + off); off += (size_t)(N_NODES + 64) * 32;  // padded
    float* e1s    = ws + off; off += (size_t)N_NODES * 4;
    float* e1d    = ws + off; off += (size_t)N_NODES * 4;
    float* rinv1  = ws + off; off += (size_t)N_NODES * 4;
    float* alpha1 = ws + off; off += (size_t)EA * 4;
    float* e2s    = ws + off; off += N_NODES;
    float* e2d    = ws + off; off += N_NODES;
    float* rinv2  = ws + off; off += N_NODES;
    float* alpha2 = ws + off; off += EA;
    _Float16* xp2h = (_Float16*)(ws + off); off += (size_t)N_NODES * 32;         // N*64 fp16
    _Float16* W1P  = (_Float16*)(ws + off); off += 8192;                         // 256*64 fp16
    _Float16* W2P  = (_Float16*)(ws + off); off += 8192;                         // 64*256 fp16
    float* va1s   = ws + off; off += 256;
    float* va1d   = ws + off; off += 256;
    float* va2s   = ws + off; off += 256;
    float* va2d   = ws + off; off += 256;
    float* pooled = ws + off; off += NG * HID;
    float* cnt    = ws + off; off += NG;
    int* rowptr   = (int*)(ws + off); off += N_NODES + 2;
    int* cursor   = (int*)(ws + off); off += N_NODES;
    int* csr_src  = (int*)(ws + off); off += EA;
    int* blksum   = (int*)(ws + off); off += NBLK;
    int* blkoff   = (int*)(ws + off); off += NBLK;
    // deg/incl alias alpha1 region (dead until k_att1; CSR build done by then)
    int* deg  = (int*)alpha1;
    int* incl = deg + N_NODES;

    const int BE = (EA + 255) / 256;
    const int BN = (N_NODES + 255) / 256;
    const int BW = (N_NODES + 3) / 4;      // wave-per-node grids
    const int BG = (N_NODES + 63) / 64;    // 64-row MFMA blocks

    hipLaunchKernelGGL(k_zero,  dim3(64),   dim3(256),  0, stream, deg, pooled, cnt);
    hipLaunchKernelGGL(k_deg,   dim3(BE),   dim3(256),  0, stream, ei, deg);
    hipLaunchKernelGGL(k_scan1, dim3(NBLK), dim3(1024), 0, stream, deg, incl, blksum);
    hipLaunchKernelGGL(k_scan2, dim3(1),    dim3(64),   0, stream, blksum, blkoff);
    hipLaunchKernelGGL(k_scan3, dim3(BN),   dim3(256),  0, stream,
                       incl, blkoff, deg, batch, rowptr, cursor, cnt);
    hipLaunchKernelGGL(k_fill,  dim3(BE),   dim3(256),  0, stream, ei, cursor, csr_src);

    hipLaunchKernelGGL(k_prepw, dim3(1),  dim3(256), 0, stream,
                       W1, a1s, a1d, W2, a2s, a2d, W1P, W2P, va1s, va1d, va2s, va2d);
    hipLaunchKernelGGL(k_prepx, dim3(BW), dim3(256), 0, stream,
                       x, va1s, va1d, xh, e1s, e1d);
    hipLaunchKernelGGL(k_gemm1, dim3(BG), dim3(256), 0, stream, xh, W1P, xp1h);
    hipLaunchKernelGGL(k_att1,  dim3(BN), dim3(256), 0, stream,
                       rowptr, csr_src, e1s, e1d, alpha1, rinv1);
    hipLaunchKernelGGL(k_aggr1, dim3(BW), dim3(256), 0, stream,
                       rowptr, csr_src, alpha1, rinv1, xp1h, b1, va2s, va2d,
                       h1h, e2s, e2d);
    hipLaunchKernelGGL(k_gemm2, dim3(BG), dim3(256), 0, stream, h1h, W2P, xp2h);
    hipLaunchKernelGGL(k_att2,  dim3(BN), dim3(256), 0, stream,
                       rowptr, csr_src, e2s, e2d, alpha2, rinv2);
    hipLaunchKernelGGL(k_aggr2, dim3(BW), dim3(256), 0, stream,
                       rowptr, csr_src, alpha2, rinv2, xp2h, b2, batch, pooled);

    hipLaunchKernelGGL(k_mlp, dim3(1), dim3(64), 0, stream,
                       pooled, cnt, Wh1, bh1, Wh2, bh2, out);
}

// Round 8
// 444.750 us; speedup vs baseline: 4.4499x; 1.1509x over previous
//
#include <hip/hip_runtime.h>
#include <math.h>

#define N_NODES 50000
#define N_EDGES 800000
#define EA (N_EDGES + N_NODES)   /* edges + self loops = 850000 */
#define HEADS 4
#define HID 64
#define NG 64
#define NEG_SLOPE 0.2f
#define SCAN_CHUNK 1024
#define NBLK ((N_NODES + SCAN_CHUNK - 1) / SCAN_CHUNK)   /* 49 */

typedef _Float16 f16x8 __attribute__((ext_vector_type(8)));
typedef float f32x4 __attribute__((ext_vector_type(4)));
struct h4 { _Float16 a, b, c, d; };   // 8-byte packed fp16 quad

__device__ inline float lrelu(float x) { return x > 0.f ? x : NEG_SLOPE * x; }

__device__ inline void edge_sd(const int* __restrict__ ei, int e, int& s, int& d) {
    if (e < N_EDGES) { s = ei[e]; d = ei[N_EDGES + e]; }
    else { s = e - N_EDGES; d = s; }
}

// MFMA 16x16x32 f16 operand fragment: lane l, elem j -> k = 16*(j>>2) + (l>>4)*4 + (j&3)
// (two glued 16x16x16 halves). p = row base (k contiguous), lq = lane>>4.
__device__ inline f16x8 ldfrag(const _Float16* __restrict__ p, int lq) {
    uint2 lo = *(const uint2*)(p + lq * 4);
    uint2 hi = *(const uint2*)(p + 16 + lq * 4);
    union { uint4 u; f16x8 v; } f;
    f.u = make_uint4(lo.x, lo.y, hi.x, hi.y);
    return f.v;
}

// ---------------- CSR build ----------------
__global__ void k_zero(int* __restrict__ deg, float* __restrict__ pooled,
                       float* __restrict__ cnt)
{
    int i = blockIdx.x * 256 + threadIdx.x;
    int st = gridDim.x * 256;
    for (int j = i; j < N_NODES; j += st) deg[j] = 0;
    if (i < NG * HID) pooled[i] = 0.f;
    if (i < NG) cnt[i] = 0.f;
}

__global__ void k_deg(const int* __restrict__ ei, int* __restrict__ deg)
{
    int e = blockIdx.x * 256 + threadIdx.x;
    if (e >= EA) return;
    int s, d; edge_sd(ei, e, s, d);
    atomicAdd(&deg[d], 1);
}

__global__ __launch_bounds__(1024) void k_scan1(const int* __restrict__ deg,
        int* __restrict__ incl, int* __restrict__ blksum)
{
    __shared__ int sd[SCAN_CHUNK];
    int t = threadIdx.x;
    int i = blockIdx.x * SCAN_CHUNK + t;
    sd[t] = (i < N_NODES) ? deg[i] : 0;
    for (int off = 1; off < SCAN_CHUNK; off <<= 1) {
        __syncthreads();
        int u = (t >= off) ? sd[t - off] : 0;
        __syncthreads();
        sd[t] += u;
    }
    if (i < N_NODES) incl[i] = sd[t];
    if (t == SCAN_CHUNK - 1) blksum[blockIdx.x] = sd[t];
}

__global__ void k_scan2(const int* __restrict__ blksum, int* __restrict__ blkoff)
{
    if (threadIdx.x == 0) {
        int acc = 0;
        for (int b = 0; b < NBLK; ++b) { blkoff[b] = acc; acc += blksum[b]; }
    }
}

__global__ void k_scan3(const int* __restrict__ incl, const int* __restrict__ blkoff,
                        const int* __restrict__ deg, const int* __restrict__ batch,
                        int* __restrict__ rowptr, int* __restrict__ cursor,
                        float* __restrict__ cnt)
{
    int i = blockIdx.x * 256 + threadIdx.x;
    bool act = i < N_NODES;
    if (act) {
        int v = incl[i] + blkoff[i >> 10];
        rowptr[i + 1] = v;
        cursor[i] = v - deg[i];
        if (i == 0) rowptr[0] = 0;
    }
    int g = act ? batch[i] : -1;
    int lane = threadIdx.x & 63;
    int g0 = __shfl(g, 0, 64);
    if (__all(g == g0)) {
        if (lane == 0 && g0 >= 0) atomicAdd(&cnt[g0], 64.f);
    } else if (act) {
        atomicAdd(&cnt[g], 1.f);
    }
}

__global__ void k_fill(const int* __restrict__ ei, int* __restrict__ cursor,
                       int* __restrict__ csr_src)
{
    int e = blockIdx.x * 256 + threadIdx.x;
    if (e >= EA) return;
    int s, d; edge_sd(ei, e, s, d);
    int pos = atomicAdd(&cursor[d], 1);
    csr_src[pos] = s;
}

// ---------- prep: fp16 weight permutes + score-projection vectors (1 block) ----------
__global__ __launch_bounds__(256) void k_prepw(const float* __restrict__ W1,
        const float* __restrict__ a1s, const float* __restrict__ a1d,
        const float* __restrict__ W2, const float* __restrict__ a2s,
        const float* __restrict__ a2d, _Float16* __restrict__ W1P,
        _Float16* __restrict__ W2P, float* __restrict__ va1s,
        float* __restrict__ va1d, float* __restrict__ va2s, float* __restrict__ va2d)
{
    const int t = threadIdx.x;
    for (int i = t; i < 256 * 64; i += 256) {
        int np = i >> 6, k = i & 63;
        W1P[i] = (_Float16)W1[k * 256 + (np & 3) * 64 + (np >> 2)];
    }
    for (int i = t; i < 64 * 256; i += 256) {
        int n = i >> 8, k = i & 255;
        W2P[i] = (_Float16)W2[k * 64 + n];
    }
    {
        int k = t >> 2, h = t & 3;
        float ss = 0.f, sd = 0.f;
        for (int c = 0; c < 64; ++c) {
            float wv = W1[k * 256 + h * 64 + c];
            ss = fmaf(wv, a1s[h * 64 + c], ss);
            sd = fmaf(wv, a1d[h * 64 + c], sd);
        }
        va1s[k * 4 + h] = ss;
        va1d[k * 4 + h] = sd;
    }
    {
        float ss = 0.f, sd = 0.f;
        for (int c = 0; c < 64; ++c) {
            float wv = W2[t * 64 + c];
            ss = fmaf(wv, a2s[c], ss);
            sd = fmaf(wv, a2d[c], sd);
        }
        va2s[t] = ss;
        va2d[t] = sd;
    }
}

// ---------- prepx: wave per node: x -> fp16, fused exact fp32 conv1 scores ----------
__global__ __launch_bounds__(256) void k_prepx(const float* __restrict__ x,
        const float* __restrict__ va1s, const float* __restrict__ va1d,
        _Float16* __restrict__ xh, float* __restrict__ e1s, float* __restrict__ e1d)
{
    const int lane = threadIdx.x & 63;
    const int w = threadIdx.x >> 6;
    const int n = blockIdx.x * 4 + w;
    if (n >= N_NODES) return;
    float xv = x[(size_t)n * 64 + lane];
    xh[(size_t)n * 64 + lane] = (_Float16)xv;
    float4 vs = ((const float4*)va1s)[lane];   // va1s[k=lane][0..3]
    float4 vd = ((const float4*)va1d)[lane];
    float s0 = xv * vs.x, s1 = xv * vs.y, s2 = xv * vs.z, s3 = xv * vs.w;
    float d0 = xv * vd.x, d1 = xv * vd.y, d2 = xv * vd.z, d3 = xv * vd.w;
    #pragma unroll
    for (int off = 32; off > 0; off >>= 1) {
        s0 += __shfl_down(s0, off, 64); s1 += __shfl_down(s1, off, 64);
        s2 += __shfl_down(s2, off, 64); s3 += __shfl_down(s3, off, 64);
        d0 += __shfl_down(d0, off, 64); d1 += __shfl_down(d1, off, 64);
        d2 += __shfl_down(d2, off, 64); d3 += __shfl_down(d3, off, 64);
    }
    if (lane == 0) {
        ((float4*)e1s)[n] = make_float4(s0, s1, s2, s3);
        ((float4*)e1d)[n] = make_float4(d0, d1, d2, d3);
    }
}

// ---------- conv1 GEMM via MFMA: xp1h[m][c*4+h] = (x @ W1)[m][h*64+c] ----------
__global__ __launch_bounds__(256) void k_gemm1(const _Float16* __restrict__ xh,
        const _Float16* __restrict__ W1P, _Float16* __restrict__ xp1h)
{
    const int t = threadIdx.x;
    const int lane = t & 63, w = t >> 6;
    const int l15 = lane & 15, lq = lane >> 4;
    const int m0 = blockIdx.x * 64 + w * 16;
    const int mrow = m0 + l15;
    const _Float16* xrow = xh + (size_t)(m0 + l15) * 64;
    f16x8 xf0 = ldfrag(xrow, lq);        // k 0..31
    f16x8 xf1 = ldfrag(xrow + 32, lq);   // k 32..63
    #pragma unroll
    for (int ct = 0; ct < 16; ++ct) {
        const _Float16* wrow = W1P + (size_t)(ct * 16 + l15) * 64;
        f16x8 wf0 = ldfrag(wrow, lq);
        f16x8 wf1 = ldfrag(wrow + 32, lq);
        f32x4 acc = {0.f, 0.f, 0.f, 0.f};
        acc = __builtin_amdgcn_mfma_f32_16x16x32_f16(wf0, xf0, acc, 0, 0, 0);
        acc = __builtin_amdgcn_mfma_f32_16x16x32_f16(wf1, xf1, acc, 0, 0, 0);
        if (mrow < N_NODES) {
            h4 o = {(_Float16)acc[0], (_Float16)acc[1], (_Float16)acc[2], (_Float16)acc[3]};
            *(h4*)(xp1h + (size_t)mrow * 256 + ct * 16 + lq * 4) = o;
        }
    }
}

// ---------- aggr1 (att fused): wave per dst, chunked shfl-broadcast gathers ----------
// Per chunk of <=64 edges: coalesced index load, parallel score gather + exp across
// lanes, then unrolled inner loop of independent 8B payload gathers.
__global__ __launch_bounds__(256) void k_aggr1(const int* __restrict__ rowptr,
        const int* __restrict__ csr_src, const float* __restrict__ e1s,
        const float* __restrict__ e1d, const _Float16* __restrict__ xp1h,
        const float* __restrict__ b1, const float* __restrict__ va2s,
        const float* __restrict__ va2d, _Float16* __restrict__ h1h,
        float* __restrict__ e2s_o, float* __restrict__ e2d_o)
{
    const int lane = threadIdx.x & 63;
    const int w = __builtin_amdgcn_readfirstlane(threadIdx.x >> 6);
    const int d = blockIdx.x * 4 + w;
    if (d >= N_NODES) return;
    const int beg = rowptr[d], end = rowptr[d + 1];
    const float4 ed = ((const float4*)e1d)[d];
    float a0 = 0.f, a1 = 0.f, a2 = 0.f, a3 = 0.f;
    float d0 = 0.f, d1 = 0.f, d2 = 0.f, d3 = 0.f;
    for (int jb = beg; jb < end; jb += 64) {
        int myj = jb + lane;
        int sv = 0;
        float4 p = make_float4(0.f, 0.f, 0.f, 0.f);
        if (myj < end) {
            sv = csr_src[myj];
            float4 q = ((const float4*)e1s)[sv];
            p.x = __expf(lrelu(q.x + ed.x));
            p.y = __expf(lrelu(q.y + ed.y));
            p.z = __expf(lrelu(q.z + ed.z));
            p.w = __expf(lrelu(q.w + ed.w));
        }
        int nj = end - jb; if (nj > 64) nj = 64;
        int njr = (nj + 3) & ~3;
        for (int j = 0; j < njr; j += 4) {
            #pragma unroll
            for (int k = 0; k < 4; ++k) {
                int s = __shfl(sv, j + k, 64);
                float px = __shfl(p.x, j + k, 64);
                float py = __shfl(p.y, j + k, 64);
                float pz = __shfl(p.z, j + k, 64);
                float pw = __shfl(p.w, j + k, 64);
                h4 xv = *(const h4*)(xp1h + (size_t)s * 256 + lane * 4);
                a0 = fmaf(px, (float)xv.a, a0);
                a1 = fmaf(py, (float)xv.b, a1);
                a2 = fmaf(pz, (float)xv.c, a2);
                a3 = fmaf(pw, (float)xv.d, a3);
                d0 += px; d1 += py; d2 += pz; d3 += pw;
            }
        }
    }
    float acc[4] = {a0 / d0, a1 / d1, a2 / d2, a3 / d3};
    float es = 0.f, edd = 0.f;
    #pragma unroll
    for (int hh = 0; hh < 4; ++hh) {
        float v = acc[hh] + b1[hh * 64 + lane];
        v = v > 0.f ? v : __expf(v) - 1.f;
        h1h[(size_t)d * 256 + hh * 64 + lane] = (_Float16)v;
        es  = fmaf(v, va2s[hh * 64 + lane], es);
        edd = fmaf(v, va2d[hh * 64 + lane], edd);
    }
    #pragma unroll
    for (int off = 32; off > 0; off >>= 1) {
        es += __shfl_down(es, off, 64);
        edd += __shfl_down(edd, off, 64);
    }
    if (lane == 0) { e2s_o[d] = es; e2d_o[d] = edd; }
}

// ---------- conv2 GEMM via MFMA: xp2h[m][n] = (h1 @ W2)[m][n] ----------
__global__ __launch_bounds__(256) void k_gemm2(const _Float16* __restrict__ h1h,
        const _Float16* __restrict__ W2P, _Float16* __restrict__ xp2h)
{
    const int t = threadIdx.x;
    const int lane = t & 63, w = t >> 6;
    const int l15 = lane & 15, lq = lane >> 4;
    const int m0 = blockIdx.x * 64 + w * 16;
    const int mrow = m0 + l15;
    const _Float16* arow = h1h + (size_t)(m0 + l15) * 256;
    f16x8 af[8];
    #pragma unroll
    for (int ks = 0; ks < 8; ++ks) af[ks] = ldfrag(arow + ks * 32, lq);
    #pragma unroll
    for (int ct = 0; ct < 4; ++ct) {
        const _Float16* wrow = W2P + (size_t)(ct * 16 + l15) * 256;
        f32x4 acc = {0.f, 0.f, 0.f, 0.f};
        #pragma unroll
        for (int ks = 0; ks < 8; ++ks) {
            f16x8 wf = ldfrag(wrow + ks * 32, lq);
            acc = __builtin_amdgcn_mfma_f32_16x16x32_f16(wf, af[ks], acc, 0, 0, 0);
        }
        if (mrow < N_NODES) {
            h4 o = {(_Float16)acc[0], (_Float16)acc[1], (_Float16)acc[2], (_Float16)acc[3]};
            *(h4*)(xp2h + (size_t)mrow * 64 + ct * 16 + lq * 4) = o;
        }
    }
}

// ---------- aggr2 (att fused): wave per dst, chunked shfl-broadcast, mean-pool ----------
__global__ __launch_bounds__(256) void k_aggr2(const int* __restrict__ rowptr,
        const int* __restrict__ csr_src, const float* __restrict__ e2s,
        const float* __restrict__ e2d, const _Float16* __restrict__ xp2h,
        const float* __restrict__ b2, const int* __restrict__ batch,
        float* __restrict__ pooled)
{
    const int lane = threadIdx.x & 63;
    const int w = __builtin_amdgcn_readfirstlane(threadIdx.x >> 6);
    const int d = blockIdx.x * 4 + w;
    if (d >= N_NODES) return;
    const int beg = rowptr[d], end = rowptr[d + 1];
    const float ed = e2d[d];
    float acc = 0.f, den = 0.f;
    for (int jb = beg; jb < end; jb += 64) {
        int myj = jb + lane;
        int sv = 0;
        float p = 0.f;
        if (myj < end) {
            sv = csr_src[myj];
            p = __expf(lrelu(e2s[sv] + ed));
        }
        int nj = end - jb; if (nj > 64) nj = 64;
        int njr = (nj + 7) & ~7;
        for (int j = 0; j < njr; j += 8) {
            #pragma unroll
            for (int k = 0; k < 8; ++k) {
                int s = __shfl(sv, j + k, 64);
                float pv = __shfl(p, j + k, 64);
                acc = fmaf(pv, (float)xp2h[(size_t)s * 64 + lane], acc);
                den += pv;
            }
        }
    }
    float val = acc / den + b2[lane];
    int g = batch[d];
    atomicAdd(&pooled[g * 64 + lane], val);
}

__global__ void k_mlp(const float* __restrict__ pooled, const float* __restrict__ cnt,
                      const float* __restrict__ Wh1, const float* __restrict__ bh1,
                      const float* __restrict__ Wh2, const float* __restrict__ bh2,
                      float* __restrict__ out)
{
    int g = threadIdx.x;   // 64 threads
    float inv = 1.f / fmaxf(cnt[g], 1.f);
    float p[64];
    #pragma unroll
    for (int c = 0; c < 64; ++c) p[c] = pooled[g * 64 + c] * inv;
    float acc2 = bh2[0];
    for (int j = 0; j < 16; ++j) {
        float z = bh1[j];
        #pragma unroll
        for (int c = 0; c < 64; ++c) z = fmaf(p[c], Wh1[c * 16 + j], z);
        z = fmaxf(z, 0.f);
        acc2 = fmaf(z, Wh2[j], acc2);
    }
    out[g] = 1.f / (1.f + expf(-acc2));
}

extern "C" void kernel_launch(void* const* d_in, const int* in_sizes, int n_in,
                              void* d_out, int out_size, void* d_ws, size_t ws_size,
                              hipStream_t stream)
{
    const float* x      = (const float*)d_in[0];
    const int*   ei     = (const int*)d_in[1];
    const int*   batch  = (const int*)d_in[2];
    const float* W1     = (const float*)d_in[3];
    const float* a1s    = (const float*)d_in[4];
    const float* a1d    = (const float*)d_in[5];
    const float* b1     = (const float*)d_in[6];
    const float* W2     = (const float*)d_in[7];
    const float* a2s    = (const float*)d_in[8];
    const float* a2d    = (const float*)d_in[9];
    const float* b2     = (const float*)d_in[10];
    const float* Wh1    = (const float*)d_in[11];
    const float* bh1    = (const float*)d_in[12];
    const float* Wh2    = (const float*)d_in[13];
    const float* bh2    = (const float*)d_in[14];
    float* out = (float*)d_out;

    float* ws = (float*)d_ws;
    size_t off = 0;
    _Float16* xp1h = (_Float16*)(ws + off); off += (size_t)N_NODES * 128;        // N*256 fp16
    _Float16* h1h  = (_Float16*)(ws + off); off += (size_t)(N_NODES + 64) * 128; // padded
    _Float16* xh   = (_Float16*)(ws + off); off += (size_t)(N_NODES + 64) * 32;  // padded
    float* e1s    = ws + off; off += (size_t)N_NODES * 4;
    float* e1d    = ws + off; off += (size_t)N_NODES * 4;
    float* e2s    = ws + off; off += N_NODES;
    float* e2d    = ws + off; off += N_NODES;
    _Float16* xp2h = (_Float16*)(ws + off); off += (size_t)N_NODES * 32;         // N*64 fp16
    _Float16* W1P  = (_Float16*)(ws + off); off += 8192;                         // 256*64 fp16
    _Float16* W2P  = (_Float16*)(ws + off); off += 8192;                         // 64*256 fp16
    float* va1s   = ws + off; off += 256;
    float* va1d   = ws + off; off += 256;
    float* va2s   = ws + off; off += 256;
    float* va2d   = ws + off; off += 256;
    float* pooled = ws + off; off += NG * HID;
    float* cnt    = ws + off; off += NG;
    int* rowptr   = (int*)(ws + off); off += N_NODES + 2;
    int* cursor   = (int*)(ws + off); off += N_NODES;
    int* csr_src  = (int*)(ws + off); off += EA;
    int* blksum   = (int*)(ws + off); off += NBLK;
    int* blkoff   = (int*)(ws + off); off += NBLK;
    // deg/incl alias h1h region (h1h not written until k_aggr1; CSR build done by then)
    int* deg  = (int*)h1h;
    int* incl = deg + N_NODES;

    const int BE = (EA + 255) / 256;
    const int BN = (N_NODES + 255) / 256;
    const int BW = (N_NODES + 3) / 4;      // wave-per-node grids
    const int BG = (N_NODES + 63) / 64;    // 64-row MFMA blocks

    hipLaunchKernelGGL(k_zero,  dim3(64),   dim3(256),  0, stream, deg, pooled, cnt);
    hipLaunchKernelGGL(k_deg,   dim3(BE),   dim3(256),  0, stream, ei, deg);
    hipLaunchKernelGGL(k_scan1, dim3(NBLK), dim3(1024), 0, stream, deg, incl, blksum);
    hipLaunchKernelGGL(k_scan2, dim3(1),    dim3(64),   0, stream, blksum, blkoff);
    hipLaunchKernelGGL(k_scan3, dim3(BN),   dim3(256),  0, stream,
                       incl, blkoff, deg, batch, rowptr, cursor, cnt);
    hipLaunchKernelGGL(k_fill,  dim3(BE),   dim3(256),  0, stream, ei, cursor, csr_src);

    hipLaunchKernelGGL(k_prepw, dim3(1),  dim3(256), 0, stream,
                       W1, a1s, a1d, W2, a2s, a2d, W1P, W2P, va1s, va1d, va2s, va2d);
    hipLaunchKernelGGL(k_prepx, dim3(BW), dim3(256), 0, stream,
                       x, va1s, va1d, xh, e1s, e1d);
    hipLaunchKernelGGL(k_gemm1, dim3(BG), dim3(256), 0, stream, xh, W1P, xp1h);
    hipLaunchKernelGGL(k_aggr1, dim3(BW), dim3(256), 0, stream,
                       rowptr, csr_src, e1s, e1d, xp1h, b1, va2s, va2d,
                       h1h, e2s, e2d);
    hipLaunchKernelGGL(k_gemm2, dim3(BG), dim3(256), 0, stream, h1h, W2P, xp2h);
    hipLaunchKernelGGL(k_aggr2, dim3(BW), dim3(256), 0, stream,
                       rowptr, csr_src, e2s, e2d, xp2h, b2, batch, pooled);

    hipLaunchKernelGGL(k_mlp, dim3(1), dim3(64), 0, stream,
                       pooled, cnt, Wh1, bh1, Wh2, bh2, out);
}